// Round 12
// baseline (418.810 us; speedup 1.0000x reference)
//
#include <hip/hip_runtime.h>

typedef unsigned int u32;
typedef unsigned short u16;
typedef __bf16 bf16x8 __attribute__((ext_vector_type(8)));
typedef float f32x16 __attribute__((ext_vector_type(16)));
typedef u32 u32x4 __attribute__((ext_vector_type(4)));
typedef _Float16 f16x2 __attribute__((ext_vector_type(2)));
typedef _Float16 f16x8 __attribute__((ext_vector_type(8)));

// K = 2*log2(e): folded into the layer-1 A-image and the BN2 scale/bias so
// tanh(x) = 1 - 2/(exp2(K*x)+1) needs zero multiplies at eval time.
#define TANH_PRESCALE 2.8853900817779268f

// ---------- helpers ----------
__device__ __forceinline__ u16 f2bf(float f) {
  u32 u = __float_as_uint(f);
  u32 r = (u + 0x7FFFu + ((u >> 16) & 1u)) >> 16;
  return (u16)r;
}
__device__ __forceinline__ float bf2f(u16 h) {
  return __uint_as_float((u32)h << 16);
}
// single-instruction RNE bf16 pack (same rounding as f2bf)
__device__ __forceinline__ u32 cvtpk_bf16(float a, float b) {
  u32 r;
  asm("v_cvt_pk_bf16_f32 %0, %1, %2" : "=v"(r) : "v"(a), "v"(b));
  return r;
}
__device__ __forceinline__ u16 f2h_bits(float a) {
  _Float16 h = (_Float16)a;
  return __builtin_bit_cast(u16, h);
}
// tanh of x where v = TANH_PRESCALE * x has been pre-folded upstream
__device__ __forceinline__ float tanh_pre(float v) {
  float e = __builtin_exp2f(v);
  return 1.0f - 2.0f * __builtin_amdgcn_rcpf(e + 1.0f);
}

// bilinear interp matching jnp.searchsorted(side='right')-1 with clamping
__device__ __forceinline__ float inter2d_d(const float* xs, const float* ys,
                                           const float* tb, float xq, float yq) {
  xq = fminf(fmaxf(xq, xs[0]), xs[8]);
  yq = fminf(fmaxf(yq, ys[0]), ys[13]);
  int i = 0, j = 0;
#pragma unroll
  for (int k = 1; k <= 8; ++k) if (xq >= xs[k]) i = k;
#pragma unroll
  for (int k = 1; k <= 13; ++k) if (yq >= ys[k]) j = k;
  if (i > 7) i = 7;
  if (j > 12) j = 12;
  float x0 = xs[i], x1 = xs[i + 1], y0 = ys[j], y1 = ys[j + 1];
  float tx = (xq - x0) / (x1 - x0);
  float ty = (yq - y0) / (y1 - y0);
  float f00 = tb[i * 14 + j], f01 = tb[i * 14 + j + 1];
  float f10 = tb[(i + 1) * 14 + j], f11 = tb[(i + 1) * 14 + j + 1];
  return f00 * (1 - tx) * (1 - ty) + f10 * tx * (1 - ty) +
         f01 * (1 - tx) * ty + f11 * tx * ty;
}

// ---------- kernel 1: merged u-moments (blocks < nstat) + w2 transpose ----------
__global__ void pre_kernel(const float* __restrict__ x,
                           const float* __restrict__ tsg,
                           const float* __restrict__ teg,
                           const float* __restrict__ tbg,
                           float* __restrict__ mom,
                           const float* __restrict__ w2,
                           unsigned char* __restrict__ w2ts, int nstat) {
  __shared__ float ts[9], te[14], tb[126], bacc[14];
  int t = threadIdx.x;
  if ((int)blockIdx.x >= nstat) {
    int q = ((int)blockIdx.x - nstat) * 256 + t;  // 0..32767
    int n = q & 511;
    int kb = (q >> 9) * 8;
    u32 pk[4];
#pragma unroll
    for (int e = 0; e < 8; e += 2) {
      u16 a = f2bf(w2[(size_t)(kb + e) * 512 + n]);
      u16 b = f2bf(w2[(size_t)(kb + e + 1) * 512 + n]);
      pk[e >> 1] = (u32)a | ((u32)b << 16);
    }
    *(uint4*)(w2ts + (size_t)q * 16) = make_uint4(pk[0], pk[1], pk[2], pk[3]);
    return;
  }
  if (t < 9) ts[t] = tsg[t];
  if (t < 14) { te[t] = teg[t]; bacc[t] = 0.f; }
  if (t < 126) tb[t] = tbg[t];
  __syncthreads();
  const float* xr = x + (size_t)(blockIdx.x * 256 + t) * 15;
  float amb = xr[1], inc = xr[8];
  float u0 = inter2d_d(ts, te, tb, xr[2], amb) - inc;
  float u1 = inter2d_d(ts, te, tb, xr[3], amb) - inc;
  float u2 = amb, u3 = xr[9] - xr[10];
  float v[14] = {u0, u1, u2, u3,
                 u0 * u0, u0 * u1, u0 * u2, u0 * u3,
                 u1 * u1, u1 * u2, u1 * u3,
                 u2 * u2, u2 * u3, u3 * u3};
#pragma unroll
  for (int i = 0; i < 14; ++i) {
    float s = v[i];
    s += __shfl_xor(s, 32); s += __shfl_xor(s, 16); s += __shfl_xor(s, 8);
    s += __shfl_xor(s, 4);  s += __shfl_xor(s, 2);  s += __shfl_xor(s, 1);
    v[i] = s;
  }
  if ((t & 63) == 0)
    for (int i = 0; i < 14; ++i) atomicAdd(&bacc[i], v[i]);
  __syncthreads();
  if (t < 14) atomicAdd(&mom[t], bacc[t]);
}

// ---------- kernel 2: fold BN1 (and tanh prescale) into layer-1 A-image ----------
__global__ void prep1_kernel(const float* __restrict__ mom,
                             const float* __restrict__ w1,
                             const float* __restrict__ g1,
                             const float* __restrict__ be1,
                             unsigned char* __restrict__ a1img, float invB) {
  int j = threadIdx.x;  // 512
  float m0 = mom[0] * invB, m1 = mom[1] * invB, m2 = mom[2] * invB, m3 = mom[3] * invB;
  float C00 = mom[4]  * invB - m0 * m0, C01 = mom[5]  * invB - m0 * m1;
  float C02 = mom[6]  * invB - m0 * m2, C03 = mom[7]  * invB - m0 * m3;
  float C11 = mom[8]  * invB - m1 * m1, C12 = mom[9]  * invB - m1 * m2;
  float C13 = mom[10] * invB - m1 * m3, C22 = mom[11] * invB - m2 * m2;
  float C23 = mom[12] * invB - m2 * m3, C33 = mom[13] * invB - m3 * m3;
  float a = w1[j], b = w1[512 + j], c = w1[1024 + j], d = w1[1536 + j];
  float var = a * a * C00 + b * b * C11 + c * c * C22 + d * d * C33 +
              2.f * (a * b * C01 + a * c * C02 + a * d * C03 +
                     b * c * C12 + b * d * C13 + c * d * C23);
  float s1 = g1[j] * rsqrtf(fmaxf(var, 0.f) + 1e-5f) * TANH_PRESCALE;
  float a0 = a * s1, a1 = b * s1, a2 = c * s1, a3 = d * s1;
  float c1j = be1[j] * TANH_PRESCALE -
              (m0 * a + m1 * b + m2 * c + m3 * d) * s1;
  u16 ba0 = f2bf(a0), ba1 = f2bf(a1), ba2 = f2bf(a2), ba3 = f2bf(a3);
  u16 da0 = f2bf(a0 - bf2f(ba0)), da1 = f2bf(a1 - bf2f(ba1));
  u16 da2 = f2bf(a2 - bf2f(ba2)), da3 = f2bf(a3 - bf2f(ba3));
  u16 c1h = f2bf(c1j);
  u16 c1l = f2bf(c1j - bf2f(c1h));
  u32 p01 = (u32)ba0 | ((u32)ba1 << 16);
  u32 p23 = (u32)ba2 | ((u32)ba3 << 16);
  uint4* img = (uint4*)a1img;
  img[j * 2]     = make_uint4(p01, p23, (u32)c1h | ((u32)da0 << 16),
                              (u32)da1 | ((u32)da2 << 16));
  img[j * 2 + 1] = make_uint4(p01, p23, (u32)c1l | ((u32)da3 << 16), 0u);
}

// ---------- pass 1: fused t1 + GEMM(t1 @ w2), stats + ROW-MAJOR t2 dump ----------
// R8 geometry (proven 216 us): 1024 threads = 16 waves = 2(M) x 8(N);
// wave tile 64x64 (2 mf x 2 nf, acc = 64 AGPR, ~4 waves/SIMD). Blocks <
// nstore additionally store t2 ROW-MAJOR fp16 via an LDS bounce:
// Phase A scatter (b16, padded stride 520 u16 -> ~2-way banks), Phase B
// conflict-free b128 reads + coalesced row-major global stores.
__global__ __launch_bounds__(1024) void gemm12_kernel(
    const float* __restrict__ x, const float* __restrict__ tsg,
    const float* __restrict__ teg, const float* __restrict__ tbg,
    const unsigned char* __restrict__ a1img,
    const unsigned char* __restrict__ w2ts, float* __restrict__ stat2,
    unsigned char* __restrict__ t2buf, int nstore) {
  __shared__ __align__(16) unsigned char sm_buf[2][33280];  // slabs + bounce pad
  __shared__ __align__(16) float sm_u[128][4];
  __shared__ float sm_ts[9], sm_te[14], sm_tb[126];

  const int t = threadIdx.x;
  const int w = t >> 6, l = t & 63;
  const int hi = l >> 5, ln = l & 31;
  const int wm = w >> 3;         // consumer row-half (rows wm*64 .. +63)
  const int wn = w & 7;          // consumer col-block (cols wn*64 .. +63)
  const int rt = w & 3;          // production batch row-tile (rows rt*32..)
  const int jt = w >> 2;         // production j-tile (local 0..3)
  const int r0 = blockIdx.x * 128;

  if (t < 9) sm_ts[t] = tsg[t];
  if (t < 14) sm_te[t] = teg[t];
  if (t < 126) sm_tb[t] = tbg[t];
  __syncthreads();

  if (t < 128) {
    const float* xr = x + (size_t)(r0 + t) * 15;
    float amb = xr[1], inc = xr[8];
    sm_u[t][0] = inter2d_d(sm_ts, sm_te, sm_tb, xr[2], amb) - inc;
    sm_u[t][1] = inter2d_d(sm_ts, sm_te, sm_tb, xr[3], amb) - inc;
    sm_u[t][2] = amb;
    sm_u[t][3] = xr[9] - xr[10];
  }
  __syncthreads();

  // u B-frag for layer-1 MFMA: lane = batch row rt*32+ln.
  bf16x8 ufrag;
  {
    float4 uv = *(const float4*)&sm_u[rt * 32 + ln][0];
    u16 b0_ = f2bf(uv.x), b1_ = f2bf(uv.y), b2_ = f2bf(uv.z), b3_ = f2bf(uv.w);
    u32x4 uq;
    if (hi == 0) {
      uq[0] = (u32)b0_ | ((u32)b1_ << 16);
      uq[1] = (u32)b2_ | ((u32)b3_ << 16);
      uq[2] = 0x00003F80u | ((u32)b0_ << 16);
      uq[3] = (u32)b1_ | ((u32)b2_ << 16);
    } else {
      u16 d0 = f2bf(uv.x - bf2f(b0_)), d1 = f2bf(uv.y - bf2f(b1_));
      u16 d2 = f2bf(uv.z - bf2f(b2_)), d3 = f2bf(uv.w - bf2f(b3_));
      uq[0] = (u32)d0 | ((u32)d1 << 16);
      uq[1] = (u32)d2 | ((u32)d3 << 16);
      uq[2] = 0x00003F80u | ((u32)b3_ << 16);
      uq[3] = 0u;
    }
    ufrag = __builtin_bit_cast(bf16x8, uq);
  }

  // each wave produces the (rt, jt) 32x32 t1 tile of slab sl
  auto produce = [&](int sl) {
    unsigned char* dst = sm_buf[sl & 1];
    bf16x8 af = *(const bf16x8*)(a1img +
        ((size_t)(sl * 128 + jt * 32 + ln) * 32 + hi * 16));
    f32x16 z = {};
    f32x16 d = __builtin_amdgcn_mfma_f32_32x32x16_bf16(af, ufrag, z, 0, 0, 0);
#pragma unroll
    for (int q = 0; q < 4; ++q) {
      u32 plo = cvtpk_bf16(tanh_pre(d[q * 4 + 0]), tanh_pre(d[q * 4 + 1]));
      u32 phi = cvtpk_bf16(tanh_pre(d[q * 4 + 2]), tanh_pre(d[q * 4 + 3]));
      *(uint2*)(dst + ((size_t)((jt * 4 + q) * 128 + rt * 32 + ln) * 16 + hi * 8)) =
          make_uint2(plo, phi);
    }
  };

  // B frag loads: global K-octet G = ks*2 + hi; cols wn*64 + nf*32 + ln
  auto loadB = [&](uint4* dst, int ks) {
    const unsigned char* p = w2ts + ((size_t)(ks * 2 + hi) * 8192) +
                             (size_t)(wn * 64 + ln) * 16;
    dst[0] = *(const uint4*)(p);
    dst[1] = *(const uint4*)(p + 512);
  };

  f32x16 acc[4];  // [mf*2+nf]
#pragma unroll
  for (int i = 0; i < 4; ++i)
#pragma unroll
    for (int k = 0; k < 16; ++k) acc[i][k] = 0.0f;

  uint4 bb[2][2];
  loadB(bb[0], 0);
  produce(0);
  __syncthreads();

#pragma unroll
  for (int sl = 0; sl < 4; ++sl) {
    const unsigned char* abuf = sm_buf[sl & 1];
#pragma unroll
    for (int s = 0; s < 8; ++s) {
      int ks = sl * 8 + s;
      if (ks < 31) loadB(bb[(ks + 1) & 1], ks + 1);
      const unsigned char* ab =
          abuf + ((size_t)(2 * s + hi) * 128 + wm * 64 + ln) * 16;
      bf16x8 a0 = *(const bf16x8*)(ab);
      bf16x8 a1 = *(const bf16x8*)(ab + 512);
#pragma unroll
      for (int nf = 0; nf < 2; ++nf) {
        bf16x8 bv = __builtin_bit_cast(bf16x8, bb[ks & 1][nf]);
        acc[0 + nf] = __builtin_amdgcn_mfma_f32_32x32x16_bf16(a0, bv, acc[0 + nf], 0, 0, 0);
        acc[2 + nf] = __builtin_amdgcn_mfma_f32_32x32x16_bf16(a1, bv, acc[2 + nf], 0, 0, 0);
      }
      if (s == 0 && sl < 3) produce(sl + 1);
    }
    __syncthreads();
  }

  // ---- row-major t2 dump via LDS bounce (blocks < nstore) ----
  // C/D layout (32x32x16): col = lane&31, row_in_tile = (k&3)+8*(k>>2)+4*hi
  if (blockIdx.x < (u32)nstore) {
    u16* lds16 = (u16*)sm_buf;  // [64 local rows][520 u16] (8-u16 pad)
#pragma unroll
    for (int mf = 0; mf < 2; ++mf) {
      // Phase A: fp16 scatter of this mf's 32 values
#pragma unroll
      for (int nf = 0; nf < 2; ++nf) {
        int col = wn * 64 + nf * 32 + ln;
#pragma unroll
        for (int k = 0; k < 16; ++k) {
          int lr = wm * 32 + (k & 3) + 8 * (k >> 2) + 4 * hi;
          lds16[lr * 520 + col] = f2h_bits(acc[mf * 2 + nf][k]);
        }
      }
      __syncthreads();
      // Phase B: conflict-free b128 reads, coalesced row-major stores
      int lr = t >> 4;                                  // 0..63
      int grow = (lr >> 5) * 64 + mf * 32 + (lr & 31);  // global row in tile
      uint4* gdst = (uint4*)(t2buf + (size_t)blockIdx.x * 131072 +
                             (size_t)grow * 1024);
      const uint4* lsrc =
          (const uint4*)((const unsigned char*)lds16 + (size_t)lr * 1040);
#pragma unroll
      for (int c = 0; c < 4; ++c) {
        int cb = (t & 15) + 16 * c;
        gdst[cb] = lsrc[cb];
      }
      __syncthreads();
    }
  }

  // column sums: wave covers rows wm*64..+63 for cols wn*64+nf*32+ln;
  // both wm halves atomically add (covers all 128 rows).
#pragma unroll
  for (int nf = 0; nf < 2; ++nf) {
    float s = 0.f, q = 0.f;
#pragma unroll
    for (int mf = 0; mf < 2; ++mf)
#pragma unroll
      for (int k = 0; k < 16; ++k) {
        float v = acc[mf * 2 + nf][k];
        s += v; q += v * v;
      }
    s += __shfl_xor(s, 32); q += __shfl_xor(q, 32);
    if (hi == 0) {
      int col = wn * 64 + nf * 32 + ln;
      atomicAdd(&stat2[col], s);
      atomicAdd(&stat2[512 + col], q);
    }
  }
}

// ---------- pass 2 (single dispatch): row-major readback for stored ----------
// ---------- tiles, recompute for the rest; BN2 fold inlined from stat2 ----------
__global__ __launch_bounds__(1024) void finish_kernel(
    const float* __restrict__ x, const float* __restrict__ tsg,
    const float* __restrict__ teg, const float* __restrict__ tbg,
    const unsigned char* __restrict__ a1img,
    const unsigned char* __restrict__ w2ts,
    const float* __restrict__ stat2,
    const unsigned char* __restrict__ t2buf,
    const float* __restrict__ g2, const float* __restrict__ be2,
    const float* __restrict__ w3g, const float* __restrict__ b3g,
    float* __restrict__ out, int nstore, float invB) {
  __shared__ __align__(16) unsigned char sm_buf[2][33280];
  __shared__ __align__(16) float sm_u[128][4];
  __shared__ float sm_ts[9], sm_te[14], sm_tb[126];

  const int t = threadIdx.x;
  const int w = t >> 6, l = t & 63;
  const int hi = l >> 5, ln = l & 31;
  const int wm = w >> 3;         // row-half (rows wm*64 .. +63)
  const int wn = w & 7;          // col-block (cols wn*64 .. +63)
  const int rt = w & 3;          // production batch row-tile
  const int jt = w >> 2;         // production j-tile
  const int r0 = blockIdx.x * 128;

  if (blockIdx.x < (u32)nstore) {
    // ---- streaming readback: row-major fp16 t2; lane l owns cols 8l..8l+7 ----
    float sv8[8], cv8[8], wv8[8];
    int cbase = l * 8;
#pragma unroll
    for (int j = 0; j < 8; ++j) {
      int col = cbase + j;
      float mu = stat2[col] * invB;
      float ex2 = stat2[512 + col] * invB;
      float var = fmaxf(ex2 - mu * mu, 0.f);
      float s = g2[col] * rsqrtf(var + 1e-5f);
      sv8[j] = s * TANH_PRESCALE;
      cv8[j] = (be2[col] - mu * s) * TANH_PRESCALE;
      wv8[j] = w3g[col];
    }
    const unsigned char* tile = t2buf + (size_t)blockIdx.x * 131072;
    float b3v = b3g[0];
#pragma unroll
    for (int rr = 0; rr < 8; ++rr) {
      int r = w * 8 + rr;  // wave handles rows w*8 .. w*8+7
      uint4 q = *(const uint4*)(tile + (size_t)r * 1024 + (size_t)l * 16);
      f16x8 qq = __builtin_bit_cast(f16x8, q);
      float v = 0.f;
#pragma unroll
      for (int j = 0; j < 8; ++j)
        v += tanh_pre((float)qq[j] * sv8[j] + cv8[j]) * wv8[j];
      v += __shfl_xor(v, 1); v += __shfl_xor(v, 2); v += __shfl_xor(v, 4);
      v += __shfl_xor(v, 8); v += __shfl_xor(v, 16); v += __shfl_xor(v, 32);
      if (l == 0) out[r0 + r] = b3v + v;
    }
    return;
  }

  // ---- recompute path: rebuild t1, GEMM, epilogue ----
  float sv[2], cv[2], wv[2];
#pragma unroll
  for (int nf = 0; nf < 2; ++nf) {
    int col = wn * 64 + nf * 32 + ln;
    float mu = stat2[col] * invB;
    float ex2 = stat2[512 + col] * invB;
    float var = fmaxf(ex2 - mu * mu, 0.f);
    float s = g2[col] * rsqrtf(var + 1e-5f);
    sv[nf] = s * TANH_PRESCALE;
    cv[nf] = (be2[col] - mu * s) * TANH_PRESCALE;
    wv[nf] = w3g[col];
  }
  float* pr = (float*)sm_buf[0];  // [128 rows][8 col-blocks]

  if (t < 9) sm_ts[t] = tsg[t];
  if (t < 14) sm_te[t] = teg[t];
  if (t < 126) sm_tb[t] = tbg[t];
  __syncthreads();

  if (t < 128) {
    const float* xr = x + (size_t)(r0 + t) * 15;
    float amb = xr[1], inc = xr[8];
    sm_u[t][0] = inter2d_d(sm_ts, sm_te, sm_tb, xr[2], amb) - inc;
    sm_u[t][1] = inter2d_d(sm_ts, sm_te, sm_tb, xr[3], amb) - inc;
    sm_u[t][2] = amb;
    sm_u[t][3] = xr[9] - xr[10];
  }
  __syncthreads();

  bf16x8 ufrag;
  {
    float4 uv = *(const float4*)&sm_u[rt * 32 + ln][0];
    u16 b0_ = f2bf(uv.x), b1_ = f2bf(uv.y), b2_ = f2bf(uv.z), b3_ = f2bf(uv.w);
    u32x4 uq;
    if (hi == 0) {
      uq[0] = (u32)b0_ | ((u32)b1_ << 16);
      uq[1] = (u32)b2_ | ((u32)b3_ << 16);
      uq[2] = 0x00003F80u | ((u32)b0_ << 16);
      uq[3] = (u32)b1_ | ((u32)b2_ << 16);
    } else {
      u16 d0 = f2bf(uv.x - bf2f(b0_)), d1 = f2bf(uv.y - bf2f(b1_));
      u16 d2 = f2bf(uv.z - bf2f(b2_)), d3 = f2bf(uv.w - bf2f(b3_));
      uq[0] = (u32)d0 | ((u32)d1 << 16);
      uq[1] = (u32)d2 | ((u32)d3 << 16);
      uq[2] = 0x00003F80u | ((u32)b3_ << 16);
      uq[3] = 0u;
    }
    ufrag = __builtin_bit_cast(bf16x8, uq);
  }

  auto produce = [&](int sl) {
    unsigned char* dst = sm_buf[sl & 1];
    bf16x8 af = *(const bf16x8*)(a1img +
        ((size_t)(sl * 128 + jt * 32 + ln) * 32 + hi * 16));
    f32x16 z = {};
    f32x16 d = __builtin_amdgcn_mfma_f32_32x32x16_bf16(af, ufrag, z, 0, 0, 0);
#pragma unroll
    for (int q = 0; q < 4; ++q) {
      u32 plo = cvtpk_bf16(tanh_pre(d[q * 4 + 0]), tanh_pre(d[q * 4 + 1]));
      u32 phi = cvtpk_bf16(tanh_pre(d[q * 4 + 2]), tanh_pre(d[q * 4 + 3]));
      *(uint2*)(dst + ((size_t)((jt * 4 + q) * 128 + rt * 32 + ln) * 16 + hi * 8)) =
          make_uint2(plo, phi);
    }
  };

  auto loadB = [&](uint4* dst, int ks) {
    const unsigned char* p = w2ts + ((size_t)(ks * 2 + hi) * 8192) +
                             (size_t)(wn * 64 + ln) * 16;
    dst[0] = *(const uint4*)(p);
    dst[1] = *(const uint4*)(p + 512);
  };

  f32x16 acc[4];
#pragma unroll
  for (int i = 0; i < 4; ++i)
#pragma unroll
    for (int k = 0; k < 16; ++k) acc[i][k] = 0.0f;

  uint4 bb[2][2];
  loadB(bb[0], 0);
  produce(0);
  __syncthreads();

#pragma unroll
  for (int sl = 0; sl < 4; ++sl) {
    const unsigned char* abuf = sm_buf[sl & 1];
#pragma unroll
    for (int s = 0; s < 8; ++s) {
      int ks = sl * 8 + s;
      if (ks < 31) loadB(bb[(ks + 1) & 1], ks + 1);
      const unsigned char* ab =
          abuf + ((size_t)(2 * s + hi) * 128 + wm * 64 + ln) * 16;
      bf16x8 a0 = *(const bf16x8*)(ab);
      bf16x8 a1 = *(const bf16x8*)(ab + 512);
#pragma unroll
      for (int nf = 0; nf < 2; ++nf) {
        bf16x8 bv = __builtin_bit_cast(bf16x8, bb[ks & 1][nf]);
        acc[0 + nf] = __builtin_amdgcn_mfma_f32_32x32x16_bf16(a0, bv, acc[0 + nf], 0, 0, 0);
        acc[2 + nf] = __builtin_amdgcn_mfma_f32_32x32x16_bf16(a1, bv, acc[2 + nf], 0, 0, 0);
      }
      if (s == 0 && sl < 3) produce(sl + 1);
    }
    __syncthreads();
  }

#pragma unroll
  for (int mf = 0; mf < 2; ++mf)
#pragma unroll
    for (int k = 0; k < 16; ++k) {
      float v = tanh_pre(acc[mf * 2 + 0][k] * sv[0] + cv[0]) * wv[0] +
                tanh_pre(acc[mf * 2 + 1][k] * sv[1] + cv[1]) * wv[1];
      v += __shfl_xor(v, 1); v += __shfl_xor(v, 2); v += __shfl_xor(v, 4);
      v += __shfl_xor(v, 8); v += __shfl_xor(v, 16);
      if (ln == 0) {
        int row = wm * 64 + mf * 32 + (k & 3) + 8 * (k >> 2) + 4 * hi;
        pr[row * 8 + wn] = v;
      }
    }
  __syncthreads();
  if (t < 128) {
    float s = b3g[0];
#pragma unroll
    for (int i = 0; i < 8; ++i) s += pr[t * 8 + i];
    out[r0 + t] = s;
  }
}

// ---------- launcher ----------
extern "C" void kernel_launch(void* const* d_in, const int* in_sizes, int n_in,
                              void* d_out, int out_size, void* d_ws, size_t ws_size,
                              hipStream_t stream) {
  const float* x   = (const float*)d_in[0];
  const float* ts  = (const float*)d_in[1];
  const float* te  = (const float*)d_in[2];
  const float* tab = (const float*)d_in[3];
  const float* w1  = (const float*)d_in[4];
  const float* g1  = (const float*)d_in[6];
  const float* be1 = (const float*)d_in[7];
  const float* w2  = (const float*)d_in[8];
  const float* g2  = (const float*)d_in[10];
  const float* be2 = (const float*)d_in[11];
  const float* w3  = (const float*)d_in[12];
  const float* b3  = (const float*)d_in[13];
  float* out = (float*)d_out;
  char* ws = (char*)d_ws;

  if (ws_size < (size_t)(32768 + 524288)) return;

  int Bn = in_sizes[0] / 15;  // 262144
  float invB = 1.0f / (float)Bn;
  int ntiles = Bn / 128;      // 2048
  int nstat = Bn / 256;       // 1024

  float* mom   = (float*)(ws + 0);      // 14 f32 (zeroed)
  float* stat2 = (float*)(ws + 64);     // 1024 f32 (zeroed)
  unsigned char* a1img = (unsigned char*)(ws + 4160);  // 16 KB (512 j x 32B)
  unsigned char* w2ts = (unsigned char*)(ws + 32768);  // 512 KB bf16 image
  unsigned char* t2buf = (unsigned char*)(ws + (1 << 20));  // fp16 t2, row-major

  // adaptive: store as many 128-row t2 tiles (128*512*2 = 128 KB each) as fit
  size_t avail = ws_size > (size_t)(1 << 20) ? ws_size - (size_t)(1 << 20) : 0;
  size_t cap = avail / 131072;
  int nstore = cap >= (size_t)ntiles ? ntiles : (int)cap;

  (void)hipMemsetAsync(ws, 0, 4160, stream);
  pre_kernel<<<nstat + 128, 256, 0, stream>>>(x, ts, te, tab, mom, w2, w2ts, nstat);
  prep1_kernel<<<1, 512, 0, stream>>>(mom, w1, g1, be1, a1img, invB);
  gemm12_kernel<<<ntiles, 1024, 0, stream>>>(x, ts, te, tab, a1img, w2ts,
                                             stat2, t2buf, nstore);
  finish_kernel<<<ntiles, 1024, 0, stream>>>(x, ts, te, tab, a1img, w2ts,
                                             stat2, t2buf, g2, be2, w3, b3,
                                             out, nstore, invB);
}

// Round 14
// 412.203 us; speedup vs baseline: 1.0160x; 1.0160x over previous
//
#include <hip/hip_runtime.h>

typedef unsigned int u32;
typedef unsigned short u16;
typedef __bf16 bf16x8 __attribute__((ext_vector_type(8)));
typedef float f32x16 __attribute__((ext_vector_type(16)));
typedef u32 u32x4 __attribute__((ext_vector_type(4)));
typedef _Float16 f16x2 __attribute__((ext_vector_type(2)));
typedef _Float16 f16x8 __attribute__((ext_vector_type(8)));

// K = 2*log2(e): folded into the layer-1 A-image and the BN2 scale/bias so
// tanh(x) = 1 - 2/(exp2(K*x)+1) needs zero multiplies at eval time.
#define TANH_PRESCALE 2.8853900817779268f

// ---------- helpers ----------
__device__ __forceinline__ u16 f2bf(float f) {
  u32 u = __float_as_uint(f);
  u32 r = (u + 0x7FFFu + ((u >> 16) & 1u)) >> 16;
  return (u16)r;
}
__device__ __forceinline__ float bf2f(u16 h) {
  return __uint_as_float((u32)h << 16);
}
// single-instruction RNE bf16 pack (same rounding as f2bf)
__device__ __forceinline__ u32 cvtpk_bf16(float a, float b) {
  u32 r;
  asm("v_cvt_pk_bf16_f32 %0, %1, %2" : "=v"(r) : "v"(a), "v"(b));
  return r;
}
__device__ __forceinline__ u32 packf16(float a, float b) {
  f16x2 h;
  h[0] = (_Float16)a;
  h[1] = (_Float16)b;
  return __builtin_bit_cast(u32, h);
}
// tanh of x where v = TANH_PRESCALE * x has been pre-folded upstream
__device__ __forceinline__ float tanh_pre(float v) {
  float e = __builtin_exp2f(v);
  return 1.0f - 2.0f * __builtin_amdgcn_rcpf(e + 1.0f);
}

// bilinear interp matching jnp.searchsorted(side='right')-1 with clamping
__device__ __forceinline__ float inter2d_d(const float* xs, const float* ys,
                                           const float* tb, float xq, float yq) {
  xq = fminf(fmaxf(xq, xs[0]), xs[8]);
  yq = fminf(fmaxf(yq, ys[0]), ys[13]);
  int i = 0, j = 0;
#pragma unroll
  for (int k = 1; k <= 8; ++k) if (xq >= xs[k]) i = k;
#pragma unroll
  for (int k = 1; k <= 13; ++k) if (yq >= ys[k]) j = k;
  if (i > 7) i = 7;
  if (j > 12) j = 12;
  float x0 = xs[i], x1 = xs[i + 1], y0 = ys[j], y1 = ys[j + 1];
  float tx = (xq - x0) / (x1 - x0);
  float ty = (yq - y0) / (y1 - y0);
  float f00 = tb[i * 14 + j], f01 = tb[i * 14 + j + 1];
  float f10 = tb[(i + 1) * 14 + j], f11 = tb[(i + 1) * 14 + j + 1];
  return f00 * (1 - tx) * (1 - ty) + f10 * tx * (1 - ty) +
         f01 * (1 - tx) * ty + f11 * tx * ty;
}

// ---------- kernel 1: merged u-moments (blocks < nstat) + w2 transpose ----------
__global__ void pre_kernel(const float* __restrict__ x,
                           const float* __restrict__ tsg,
                           const float* __restrict__ teg,
                           const float* __restrict__ tbg,
                           float* __restrict__ mom,
                           const float* __restrict__ w2,
                           unsigned char* __restrict__ w2ts, int nstat) {
  __shared__ float ts[9], te[14], tb[126], bacc[14];
  int t = threadIdx.x;
  if ((int)blockIdx.x >= nstat) {
    int q = ((int)blockIdx.x - nstat) * 256 + t;  // 0..32767
    int n = q & 511;
    int kb = (q >> 9) * 8;
    u32 pk[4];
#pragma unroll
    for (int e = 0; e < 8; e += 2) {
      u16 a = f2bf(w2[(size_t)(kb + e) * 512 + n]);
      u16 b = f2bf(w2[(size_t)(kb + e + 1) * 512 + n]);
      pk[e >> 1] = (u32)a | ((u32)b << 16);
    }
    *(uint4*)(w2ts + (size_t)q * 16) = make_uint4(pk[0], pk[1], pk[2], pk[3]);
    return;
  }
  if (t < 9) ts[t] = tsg[t];
  if (t < 14) { te[t] = teg[t]; bacc[t] = 0.f; }
  if (t < 126) tb[t] = tbg[t];
  __syncthreads();
  const float* xr = x + (size_t)(blockIdx.x * 256 + t) * 15;
  float amb = xr[1], inc = xr[8];
  float u0 = inter2d_d(ts, te, tb, xr[2], amb) - inc;
  float u1 = inter2d_d(ts, te, tb, xr[3], amb) - inc;
  float u2 = amb, u3 = xr[9] - xr[10];
  float v[14] = {u0, u1, u2, u3,
                 u0 * u0, u0 * u1, u0 * u2, u0 * u3,
                 u1 * u1, u1 * u2, u1 * u3,
                 u2 * u2, u2 * u3, u3 * u3};
#pragma unroll
  for (int i = 0; i < 14; ++i) {
    float s = v[i];
    s += __shfl_xor(s, 32); s += __shfl_xor(s, 16); s += __shfl_xor(s, 8);
    s += __shfl_xor(s, 4);  s += __shfl_xor(s, 2);  s += __shfl_xor(s, 1);
    v[i] = s;
  }
  if ((t & 63) == 0)
    for (int i = 0; i < 14; ++i) atomicAdd(&bacc[i], v[i]);
  __syncthreads();
  if (t < 14) atomicAdd(&mom[t], bacc[t]);
}

// ---------- kernel 2: fold BN1 (and tanh prescale) into layer-1 A-image ----------
__global__ void prep1_kernel(const float* __restrict__ mom,
                             const float* __restrict__ w1,
                             const float* __restrict__ g1,
                             const float* __restrict__ be1,
                             unsigned char* __restrict__ a1img, float invB) {
  int j = threadIdx.x;  // 512
  float m0 = mom[0] * invB, m1 = mom[1] * invB, m2 = mom[2] * invB, m3 = mom[3] * invB;
  float C00 = mom[4]  * invB - m0 * m0, C01 = mom[5]  * invB - m0 * m1;
  float C02 = mom[6]  * invB - m0 * m2, C03 = mom[7]  * invB - m0 * m3;
  float C11 = mom[8]  * invB - m1 * m1, C12 = mom[9]  * invB - m1 * m2;
  float C13 = mom[10] * invB - m1 * m3, C22 = mom[11] * invB - m2 * m2;
  float C23 = mom[12] * invB - m2 * m3, C33 = mom[13] * invB - m3 * m3;
  float a = w1[j], b = w1[512 + j], c = w1[1024 + j], d = w1[1536 + j];
  float var = a * a * C00 + b * b * C11 + c * c * C22 + d * d * C33 +
              2.f * (a * b * C01 + a * c * C02 + a * d * C03 +
                     b * c * C12 + b * d * C13 + c * d * C23);
  float s1 = g1[j] * rsqrtf(fmaxf(var, 0.f) + 1e-5f) * TANH_PRESCALE;
  float a0 = a * s1, a1 = b * s1, a2 = c * s1, a3 = d * s1;
  float c1j = be1[j] * TANH_PRESCALE -
              (m0 * a + m1 * b + m2 * c + m3 * d) * s1;
  u16 ba0 = f2bf(a0), ba1 = f2bf(a1), ba2 = f2bf(a2), ba3 = f2bf(a3);
  u16 da0 = f2bf(a0 - bf2f(ba0)), da1 = f2bf(a1 - bf2f(ba1));
  u16 da2 = f2bf(a2 - bf2f(ba2)), da3 = f2bf(a3 - bf2f(ba3));
  u16 c1h = f2bf(c1j);
  u16 c1l = f2bf(c1j - bf2f(c1h));
  u32 p01 = (u32)ba0 | ((u32)ba1 << 16);
  u32 p23 = (u32)ba2 | ((u32)ba3 << 16);
  uint4* img = (uint4*)a1img;
  img[j * 2]     = make_uint4(p01, p23, (u32)c1h | ((u32)da0 << 16),
                              (u32)da1 | ((u32)da2 << 16));
  img[j * 2 + 1] = make_uint4(p01, p23, (u32)c1l | ((u32)da3 << 16), 0u);
}

// ---------- pass 1: fused t1 + GEMM(t1 @ w2), stats + fragment t2 dump ----------
// R8/R11 geometry (proven 216 us): 1024 threads = 16 waves = 2(M) x 8(N);
// wave tile 64x64 (2 mf x 2 nf, acc = 64 AGPR, ~4 waves/SIMD). Blocks <
// nstore store fp16 t2 fragments [chunk][tid]-interleaved (coalesced 16B).
__global__ __launch_bounds__(1024) void gemm12_kernel(
    const float* __restrict__ x, const float* __restrict__ tsg,
    const float* __restrict__ teg, const float* __restrict__ tbg,
    const unsigned char* __restrict__ a1img,
    const unsigned char* __restrict__ w2ts, float* __restrict__ stat2,
    unsigned char* __restrict__ t2buf, int nstore) {
  __shared__ __align__(16) unsigned char sm_buf[2][32768];  // t1 slabs, chunk-major
  __shared__ __align__(16) float sm_u[128][4];
  __shared__ float sm_ts[9], sm_te[14], sm_tb[126];

  const int t = threadIdx.x;
  const int w = t >> 6, l = t & 63;
  const int hi = l >> 5, ln = l & 31;
  const int wm = w >> 3;         // consumer row-half (rows wm*64 .. +63)
  const int wn = w & 7;          // consumer col-block (cols wn*64 .. +63)
  const int rt = w & 3;          // production batch row-tile (rows rt*32..)
  const int jt = w >> 2;         // production j-tile (local 0..3)
  const int r0 = blockIdx.x * 128;

  if (t < 9) sm_ts[t] = tsg[t];
  if (t < 14) sm_te[t] = teg[t];
  if (t < 126) sm_tb[t] = tbg[t];
  __syncthreads();

  if (t < 128) {
    const float* xr = x + (size_t)(r0 + t) * 15;
    float amb = xr[1], inc = xr[8];
    sm_u[t][0] = inter2d_d(sm_ts, sm_te, sm_tb, xr[2], amb) - inc;
    sm_u[t][1] = inter2d_d(sm_ts, sm_te, sm_tb, xr[3], amb) - inc;
    sm_u[t][2] = amb;
    sm_u[t][3] = xr[9] - xr[10];
  }
  __syncthreads();

  // u B-frag for layer-1 MFMA: lane = batch row rt*32+ln.
  bf16x8 ufrag;
  {
    float4 uv = *(const float4*)&sm_u[rt * 32 + ln][0];
    u16 b0_ = f2bf(uv.x), b1_ = f2bf(uv.y), b2_ = f2bf(uv.z), b3_ = f2bf(uv.w);
    u32x4 uq;
    if (hi == 0) {
      uq[0] = (u32)b0_ | ((u32)b1_ << 16);
      uq[1] = (u32)b2_ | ((u32)b3_ << 16);
      uq[2] = 0x00003F80u | ((u32)b0_ << 16);
      uq[3] = (u32)b1_ | ((u32)b2_ << 16);
    } else {
      u16 d0 = f2bf(uv.x - bf2f(b0_)), d1 = f2bf(uv.y - bf2f(b1_));
      u16 d2 = f2bf(uv.z - bf2f(b2_)), d3 = f2bf(uv.w - bf2f(b3_));
      uq[0] = (u32)d0 | ((u32)d1 << 16);
      uq[1] = (u32)d2 | ((u32)d3 << 16);
      uq[2] = 0x00003F80u | ((u32)b3_ << 16);
      uq[3] = 0u;
    }
    ufrag = __builtin_bit_cast(bf16x8, uq);
  }

  // each wave produces the (rt, jt) 32x32 t1 tile of slab sl
  auto produce = [&](int sl) {
    unsigned char* dst = sm_buf[sl & 1];
    bf16x8 af = *(const bf16x8*)(a1img +
        ((size_t)(sl * 128 + jt * 32 + ln) * 32 + hi * 16));
    f32x16 z = {};
    f32x16 d = __builtin_amdgcn_mfma_f32_32x32x16_bf16(af, ufrag, z, 0, 0, 0);
#pragma unroll
    for (int q = 0; q < 4; ++q) {
      u32 plo = cvtpk_bf16(tanh_pre(d[q * 4 + 0]), tanh_pre(d[q * 4 + 1]));
      u32 phi = cvtpk_bf16(tanh_pre(d[q * 4 + 2]), tanh_pre(d[q * 4 + 3]));
      *(uint2*)(dst + ((size_t)((jt * 4 + q) * 128 + rt * 32 + ln) * 16 + hi * 8)) =
          make_uint2(plo, phi);
    }
  };

  // B frag loads: global K-octet G = ks*2 + hi; cols wn*64 + nf*32 + ln
  auto loadB = [&](uint4* dst, int ks) {
    const unsigned char* p = w2ts + ((size_t)(ks * 2 + hi) * 8192) +
                             (size_t)(wn * 64 + ln) * 16;
    dst[0] = *(const uint4*)(p);
    dst[1] = *(const uint4*)(p + 512);
  };

  f32x16 acc[4];  // [mf*2+nf]
#pragma unroll
  for (int i = 0; i < 4; ++i)
#pragma unroll
    for (int k = 0; k < 16; ++k) acc[i][k] = 0.0f;

  uint4 bb[2][2];
  loadB(bb[0], 0);
  produce(0);
  __syncthreads();

#pragma unroll
  for (int sl = 0; sl < 4; ++sl) {
    const unsigned char* abuf = sm_buf[sl & 1];
#pragma unroll
    for (int s = 0; s < 8; ++s) {
      int ks = sl * 8 + s;
      if (ks < 31) loadB(bb[(ks + 1) & 1], ks + 1);
      const unsigned char* ab =
          abuf + ((size_t)(2 * s + hi) * 128 + wm * 64 + ln) * 16;
      bf16x8 a0 = *(const bf16x8*)(ab);
      bf16x8 a1 = *(const bf16x8*)(ab + 512);
#pragma unroll
      for (int nf = 0; nf < 2; ++nf) {
        bf16x8 bv = __builtin_bit_cast(bf16x8, bb[ks & 1][nf]);
        acc[0 + nf] = __builtin_amdgcn_mfma_f32_32x32x16_bf16(a0, bv, acc[0 + nf], 0, 0, 0);
        acc[2 + nf] = __builtin_amdgcn_mfma_f32_32x32x16_bf16(a1, bv, acc[2 + nf], 0, 0, 0);
      }
      if (s == 0 && sl < 3) produce(sl + 1);
    }
    __syncthreads();
  }

  // C/D layout (32x32x16): col = lane&31, row_in_tile = (k&3) + 8*(k>>2) + 4*hi
  if (blockIdx.x < (u32)nstore) {
    // fp16 t2 fragments, [chunk][tid] interleave (coalesced 16B stores)
    uint4* dst = (uint4*)(t2buf + (size_t)blockIdx.x * 131072);
#pragma unroll
    for (int i = 0; i < 4; ++i)
#pragma unroll
      for (int h2 = 0; h2 < 2; ++h2) {
        uint4 pk4;
        pk4.x = packf16(acc[i][h2 * 8 + 0], acc[i][h2 * 8 + 1]);
        pk4.y = packf16(acc[i][h2 * 8 + 2], acc[i][h2 * 8 + 3]);
        pk4.z = packf16(acc[i][h2 * 8 + 4], acc[i][h2 * 8 + 5]);
        pk4.w = packf16(acc[i][h2 * 8 + 6], acc[i][h2 * 8 + 7]);
        dst[(i * 2 + h2) * 1024 + t] = pk4;
      }
  }
  // column sums: wave covers rows wm*64..+63 for cols wn*64+nf*32+ln;
  // both wm halves atomically add (covers all 128 rows).
#pragma unroll
  for (int nf = 0; nf < 2; ++nf) {
    float s = 0.f, q = 0.f;
#pragma unroll
    for (int mf = 0; mf < 2; ++mf)
#pragma unroll
      for (int k = 0; k < 16; ++k) {
        float v = acc[mf * 2 + nf][k];
        s += v; q += v * v;
      }
    s += __shfl_xor(s, 32); q += __shfl_xor(q, 32);
    if (hi == 0) {
      int col = wn * 64 + nf * 32 + ln;
      atomicAdd(&stat2[col], s);
      atomicAdd(&stat2[512 + col], q);
    }
  }
}

// ---------- pass 2a: readback stored tiles (grid = nstore) ----------
// R11's proven readback branch, verbatim: fragment loads, per-lane tanh,
// 5-level shfl reduce into pr[row][wn], final 8-way sum. No type punning.
__global__ __launch_bounds__(1024) void finish_rb(
    const float* __restrict__ stat2,
    const unsigned char* __restrict__ t2buf,
    const float* __restrict__ g2, const float* __restrict__ be2,
    const float* __restrict__ w3g, const float* __restrict__ b3g,
    float* __restrict__ out, float invB) {
  __shared__ float pr[128 * 8];
  const int t = threadIdx.x;
  const int w = t >> 6, l = t & 63;
  const int hi = l >> 5, ln = l & 31;
  const int wm = w >> 3, wn = w & 7;
  const int r0 = blockIdx.x * 128;

  float sv[2], cv[2], wv[2];
#pragma unroll
  for (int nf = 0; nf < 2; ++nf) {
    int col = wn * 64 + nf * 32 + ln;
    float mu = stat2[col] * invB;
    float ex2 = stat2[512 + col] * invB;
    float var = fmaxf(ex2 - mu * mu, 0.f);
    float s = g2[col] * rsqrtf(var + 1e-5f);
    sv[nf] = s * TANH_PRESCALE;
    cv[nf] = (be2[col] - mu * s) * TANH_PRESCALE;
    wv[nf] = w3g[col];
  }
  const uint4* src = (const uint4*)(t2buf + (size_t)blockIdx.x * 131072);
#pragma unroll
  for (int mf = 0; mf < 2; ++mf) {
    uint4 q[2][2];
#pragma unroll
    for (int nf = 0; nf < 2; ++nf)
#pragma unroll
      for (int h2 = 0; h2 < 2; ++h2)
        q[nf][h2] = src[((mf * 2 + nf) * 2 + h2) * 1024 + t];
#pragma unroll
    for (int k = 0; k < 16; ++k) {
      float v = 0.f;
#pragma unroll
      for (int nf = 0; nf < 2; ++nf) {
        f16x8 qq = __builtin_bit_cast(f16x8, q[nf][k >> 3]);
        float a0 = (float)qq[k & 7];
        v += tanh_pre(a0 * sv[nf] + cv[nf]) * wv[nf];
      }
      v += __shfl_xor(v, 1); v += __shfl_xor(v, 2); v += __shfl_xor(v, 4);
      v += __shfl_xor(v, 8); v += __shfl_xor(v, 16);
      if (ln == 0) {
        int row = wm * 64 + mf * 32 + (k & 3) + 8 * (k >> 2) + 4 * hi;
        pr[row * 8 + wn] = v;
      }
    }
  }
  __syncthreads();
  if (t < 128) {
    float s = b3g[0];
#pragma unroll
    for (int i = 0; i < 8; ++i) s += pr[t * 8 + i];
    out[r0 + t] = s;
  }
}

// ---------- pass 2b: recompute tiles (grid = ntiles - nstore, offset blk0) ----------
// R11's proven recompute branch with the R10-proven blk0 row offset.
__global__ __launch_bounds__(1024) void finish_rc(
    const float* __restrict__ x, const float* __restrict__ tsg,
    const float* __restrict__ teg, const float* __restrict__ tbg,
    const unsigned char* __restrict__ a1img,
    const unsigned char* __restrict__ w2ts,
    const float* __restrict__ stat2,
    const float* __restrict__ g2, const float* __restrict__ be2,
    const float* __restrict__ w3g, const float* __restrict__ b3g,
    float* __restrict__ out, int blk0, float invB) {
  __shared__ __align__(16) unsigned char sm_buf[2][32768];
  __shared__ __align__(16) float sm_u[128][4];
  __shared__ float sm_ts[9], sm_te[14], sm_tb[126];

  const int t = threadIdx.x;
  const int w = t >> 6, l = t & 63;
  const int hi = l >> 5, ln = l & 31;
  const int wm = w >> 3;
  const int wn = w & 7;
  const int rt = w & 3;
  const int jt = w >> 2;
  const int r0 = (blockIdx.x + blk0) * 128;

  float sv[2], cv[2], wv[2];
#pragma unroll
  for (int nf = 0; nf < 2; ++nf) {
    int col = wn * 64 + nf * 32 + ln;
    float mu = stat2[col] * invB;
    float ex2 = stat2[512 + col] * invB;
    float var = fmaxf(ex2 - mu * mu, 0.f);
    float s = g2[col] * rsqrtf(var + 1e-5f);
    sv[nf] = s * TANH_PRESCALE;
    cv[nf] = (be2[col] - mu * s) * TANH_PRESCALE;
    wv[nf] = w3g[col];
  }

  if (t < 9) sm_ts[t] = tsg[t];
  if (t < 14) sm_te[t] = teg[t];
  if (t < 126) sm_tb[t] = tbg[t];
  __syncthreads();

  if (t < 128) {
    const float* xr = x + (size_t)(r0 + t) * 15;
    float amb = xr[1], inc = xr[8];
    sm_u[t][0] = inter2d_d(sm_ts, sm_te, sm_tb, xr[2], amb) - inc;
    sm_u[t][1] = inter2d_d(sm_ts, sm_te, sm_tb, xr[3], amb) - inc;
    sm_u[t][2] = amb;
    sm_u[t][3] = xr[9] - xr[10];
  }
  __syncthreads();

  bf16x8 ufrag;
  {
    float4 uv = *(const float4*)&sm_u[rt * 32 + ln][0];
    u16 b0_ = f2bf(uv.x), b1_ = f2bf(uv.y), b2_ = f2bf(uv.z), b3_ = f2bf(uv.w);
    u32x4 uq;
    if (hi == 0) {
      uq[0] = (u32)b0_ | ((u32)b1_ << 16);
      uq[1] = (u32)b2_ | ((u32)b3_ << 16);
      uq[2] = 0x00003F80u | ((u32)b0_ << 16);
      uq[3] = (u32)b1_ | ((u32)b2_ << 16);
    } else {
      u16 d0 = f2bf(uv.x - bf2f(b0_)), d1 = f2bf(uv.y - bf2f(b1_));
      u16 d2 = f2bf(uv.z - bf2f(b2_)), d3 = f2bf(uv.w - bf2f(b3_));
      uq[0] = (u32)d0 | ((u32)d1 << 16);
      uq[1] = (u32)d2 | ((u32)d3 << 16);
      uq[2] = 0x00003F80u | ((u32)b3_ << 16);
      uq[3] = 0u;
    }
    ufrag = __builtin_bit_cast(bf16x8, uq);
  }

  auto produce = [&](int sl) {
    unsigned char* dst = sm_buf[sl & 1];
    bf16x8 af = *(const bf16x8*)(a1img +
        ((size_t)(sl * 128 + jt * 32 + ln) * 32 + hi * 16));
    f32x16 z = {};
    f32x16 d = __builtin_amdgcn_mfma_f32_32x32x16_bf16(af, ufrag, z, 0, 0, 0);
#pragma unroll
    for (int q = 0; q < 4; ++q) {
      u32 plo = cvtpk_bf16(tanh_pre(d[q * 4 + 0]), tanh_pre(d[q * 4 + 1]));
      u32 phi = cvtpk_bf16(tanh_pre(d[q * 4 + 2]), tanh_pre(d[q * 4 + 3]));
      *(uint2*)(dst + ((size_t)((jt * 4 + q) * 128 + rt * 32 + ln) * 16 + hi * 8)) =
          make_uint2(plo, phi);
    }
  };

  auto loadB = [&](uint4* dst, int ks) {
    const unsigned char* p = w2ts + ((size_t)(ks * 2 + hi) * 8192) +
                             (size_t)(wn * 64 + ln) * 16;
    dst[0] = *(const uint4*)(p);
    dst[1] = *(const uint4*)(p + 512);
  };

  f32x16 acc[4];
#pragma unroll
  for (int i = 0; i < 4; ++i)
#pragma unroll
    for (int k = 0; k < 16; ++k) acc[i][k] = 0.0f;

  uint4 bb[2][2];
  loadB(bb[0], 0);
  produce(0);
  __syncthreads();

#pragma unroll
  for (int sl = 0; sl < 4; ++sl) {
    const unsigned char* abuf = sm_buf[sl & 1];
#pragma unroll
    for (int s = 0; s < 8; ++s) {
      int ks = sl * 8 + s;
      if (ks < 31) loadB(bb[(ks + 1) & 1], ks + 1);
      const unsigned char* ab =
          abuf + ((size_t)(2 * s + hi) * 128 + wm * 64 + ln) * 16;
      bf16x8 a0 = *(const bf16x8*)(ab);
      bf16x8 a1 = *(const bf16x8*)(ab + 512);
#pragma unroll
      for (int nf = 0; nf < 2; ++nf) {
        bf16x8 bv = __builtin_bit_cast(bf16x8, bb[ks & 1][nf]);
        acc[0 + nf] = __builtin_amdgcn_mfma_f32_32x32x16_bf16(a0, bv, acc[0 + nf], 0, 0, 0);
        acc[2 + nf] = __builtin_amdgcn_mfma_f32_32x32x16_bf16(a1, bv, acc[2 + nf], 0, 0, 0);
      }
      if (s == 0 && sl < 3) produce(sl + 1);
    }
    __syncthreads();
  }

  float* pr = (float*)sm_buf[0];  // [128 rows][8 col-blocks]
#pragma unroll
  for (int mf = 0; mf < 2; ++mf)
#pragma unroll
    for (int k = 0; k < 16; ++k) {
      float v = tanh_pre(acc[mf * 2 + 0][k] * sv[0] + cv[0]) * wv[0] +
                tanh_pre(acc[mf * 2 + 1][k] * sv[1] + cv[1]) * wv[1];
      v += __shfl_xor(v, 1); v += __shfl_xor(v, 2); v += __shfl_xor(v, 4);
      v += __shfl_xor(v, 8); v += __shfl_xor(v, 16);
      if (ln == 0) {
        int row = wm * 64 + mf * 32 + (k & 3) + 8 * (k >> 2) + 4 * hi;
        pr[row * 8 + wn] = v;
      }
    }
  __syncthreads();
  if (t < 128) {
    float s = b3g[0];
#pragma unroll
    for (int i = 0; i < 8; ++i) s += pr[t * 8 + i];
    out[r0 + t] = s;
  }
}

// ---------- launcher ----------
extern "C" void kernel_launch(void* const* d_in, const int* in_sizes, int n_in,
                              void* d_out, int out_size, void* d_ws, size_t ws_size,
                              hipStream_t stream) {
  const float* x   = (const float*)d_in[0];
  const float* ts  = (const float*)d_in[1];
  const float* te  = (const float*)d_in[2];
  const float* tab = (const float*)d_in[3];
  const float* w1  = (const float*)d_in[4];
  const float* g1  = (const float*)d_in[6];
  const float* be1 = (const float*)d_in[7];
  const float* w2  = (const float*)d_in[8];
  const float* g2  = (const float*)d_in[10];
  const float* be2 = (const float*)d_in[11];
  const float* w3  = (const float*)d_in[12];
  const float* b3  = (const float*)d_in[13];
  float* out = (float*)d_out;
  char* ws = (char*)d_ws;

  if (ws_size < (size_t)(32768 + 524288)) return;

  int Bn = in_sizes[0] / 15;  // 262144
  float invB = 1.0f / (float)Bn;
  int ntiles = Bn / 128;      // 2048
  int nstat = Bn / 256;       // 1024

  float* mom   = (float*)(ws + 0);      // 14 f32 (zeroed)
  float* stat2 = (float*)(ws + 64);     // 1024 f32 (zeroed)
  unsigned char* a1img = (unsigned char*)(ws + 4160);  // 16 KB (512 j x 32B)
  unsigned char* w2ts = (unsigned char*)(ws + 32768);  // 512 KB bf16 image
  unsigned char* t2buf = (unsigned char*)(ws + (1 << 20));  // fp16 t2 (adaptive)

  // adaptive: store as many 128-row t2 tiles (128*512*2 = 128 KB each) as fit
  size_t avail = ws_size > (size_t)(1 << 20) ? ws_size - (size_t)(1 << 20) : 0;
  size_t cap = avail / 131072;
  int nstore = cap >= (size_t)ntiles ? ntiles : (int)cap;

  (void)hipMemsetAsync(ws, 0, 4160, stream);
  pre_kernel<<<nstat + 128, 256, 0, stream>>>(x, ts, te, tab, mom, w2, w2ts, nstat);
  prep1_kernel<<<1, 512, 0, stream>>>(mom, w1, g1, be1, a1img, invB);
  gemm12_kernel<<<ntiles, 1024, 0, stream>>>(x, ts, te, tab, a1img, w2ts,
                                             stat2, t2buf, nstore);
  if (nstore > 0)
    finish_rb<<<nstore, 1024, 0, stream>>>(stat2, t2buf, g2, be2, w3, b3,
                                           out, invB);
  if (nstore < ntiles)
    finish_rc<<<ntiles - nstore, 1024, 0, stream>>>(
        x, ts, te, tab, a1img, w2ts, stat2, g2, be2, w3, b3, out,
        nstore, invB);
}

// Round 15
// 412.009 us; speedup vs baseline: 1.0165x; 1.0005x over previous
//
#include <hip/hip_runtime.h>

typedef unsigned int u32;
typedef unsigned short u16;
typedef __bf16 bf16x8 __attribute__((ext_vector_type(8)));
typedef float f32x16 __attribute__((ext_vector_type(16)));
typedef u32 u32x4 __attribute__((ext_vector_type(4)));
typedef _Float16 f16x2 __attribute__((ext_vector_type(2)));
typedef _Float16 f16x8 __attribute__((ext_vector_type(8)));

// K = 2*log2(e): folded into the layer-1 A-image and the BN2 scale/bias so
// tanh(x) = 1 - 2/(exp2(K*x)+1) needs zero multiplies at eval time.
#define TANH_PRESCALE 2.8853900817779268f

// ---------- helpers ----------
__device__ __forceinline__ u16 f2bf(float f) {
  u32 u = __float_as_uint(f);
  u32 r = (u + 0x7FFFu + ((u >> 16) & 1u)) >> 16;
  return (u16)r;
}
__device__ __forceinline__ float bf2f(u16 h) {
  return __uint_as_float((u32)h << 16);
}
// single-instruction RNE bf16 pack (same rounding as f2bf)
__device__ __forceinline__ u32 cvtpk_bf16(float a, float b) {
  u32 r;
  asm("v_cvt_pk_bf16_f32 %0, %1, %2" : "=v"(r) : "v"(a), "v"(b));
  return r;
}
__device__ __forceinline__ u32 packf16(float a, float b) {
  f16x2 h;
  h[0] = (_Float16)a;
  h[1] = (_Float16)b;
  return __builtin_bit_cast(u32, h);
}
// tanh of x where v = TANH_PRESCALE * x has been pre-folded upstream
__device__ __forceinline__ float tanh_pre(float v) {
  float e = __builtin_exp2f(v);
  return 1.0f - 2.0f * __builtin_amdgcn_rcpf(e + 1.0f);
}

// bilinear interp matching jnp.searchsorted(side='right')-1 with clamping
__device__ __forceinline__ float inter2d_d(const float* xs, const float* ys,
                                           const float* tb, float xq, float yq) {
  xq = fminf(fmaxf(xq, xs[0]), xs[8]);
  yq = fminf(fmaxf(yq, ys[0]), ys[13]);
  int i = 0, j = 0;
#pragma unroll
  for (int k = 1; k <= 8; ++k) if (xq >= xs[k]) i = k;
#pragma unroll
  for (int k = 1; k <= 13; ++k) if (yq >= ys[k]) j = k;
  if (i > 7) i = 7;
  if (j > 12) j = 12;
  float x0 = xs[i], x1 = xs[i + 1], y0 = ys[j], y1 = ys[j + 1];
  float tx = (xq - x0) / (x1 - x0);
  float ty = (yq - y0) / (y1 - y0);
  float f00 = tb[i * 14 + j], f01 = tb[i * 14 + j + 1];
  float f10 = tb[(i + 1) * 14 + j], f11 = tb[(i + 1) * 14 + j + 1];
  return f00 * (1 - tx) * (1 - ty) + f10 * tx * (1 - ty) +
         f01 * (1 - tx) * ty + f11 * tx * ty;
}

// ---------- kernel 1: merged u-moments (blocks < nstat) + w2 transpose ----------
__global__ void pre_kernel(const float* __restrict__ x,
                           const float* __restrict__ tsg,
                           const float* __restrict__ teg,
                           const float* __restrict__ tbg,
                           float* __restrict__ mom,
                           const float* __restrict__ w2,
                           unsigned char* __restrict__ w2ts, int nstat) {
  __shared__ float ts[9], te[14], tb[126], bacc[14];
  int t = threadIdx.x;
  if ((int)blockIdx.x >= nstat) {
    int q = ((int)blockIdx.x - nstat) * 256 + t;  // 0..32767
    int n = q & 511;
    int kb = (q >> 9) * 8;
    u32 pk[4];
#pragma unroll
    for (int e = 0; e < 8; e += 2) {
      u16 a = f2bf(w2[(size_t)(kb + e) * 512 + n]);
      u16 b = f2bf(w2[(size_t)(kb + e + 1) * 512 + n]);
      pk[e >> 1] = (u32)a | ((u32)b << 16);
    }
    *(uint4*)(w2ts + (size_t)q * 16) = make_uint4(pk[0], pk[1], pk[2], pk[3]);
    return;
  }
  if (t < 9) ts[t] = tsg[t];
  if (t < 14) { te[t] = teg[t]; bacc[t] = 0.f; }
  if (t < 126) tb[t] = tbg[t];
  __syncthreads();
  const float* xr = x + (size_t)(blockIdx.x * 256 + t) * 15;
  float amb = xr[1], inc = xr[8];
  float u0 = inter2d_d(ts, te, tb, xr[2], amb) - inc;
  float u1 = inter2d_d(ts, te, tb, xr[3], amb) - inc;
  float u2 = amb, u3 = xr[9] - xr[10];
  float v[14] = {u0, u1, u2, u3,
                 u0 * u0, u0 * u1, u0 * u2, u0 * u3,
                 u1 * u1, u1 * u2, u1 * u3,
                 u2 * u2, u2 * u3, u3 * u3};
#pragma unroll
  for (int i = 0; i < 14; ++i) {
    float s = v[i];
    s += __shfl_xor(s, 32); s += __shfl_xor(s, 16); s += __shfl_xor(s, 8);
    s += __shfl_xor(s, 4);  s += __shfl_xor(s, 2);  s += __shfl_xor(s, 1);
    v[i] = s;
  }
  if ((t & 63) == 0)
    for (int i = 0; i < 14; ++i) atomicAdd(&bacc[i], v[i]);
  __syncthreads();
  if (t < 14) atomicAdd(&mom[t], bacc[t]);
}

// ---------- kernel 2: fold BN1 (and tanh prescale) into layer-1 A-image ----------
__global__ void prep1_kernel(const float* __restrict__ mom,
                             const float* __restrict__ w1,
                             const float* __restrict__ g1,
                             const float* __restrict__ be1,
                             unsigned char* __restrict__ a1img, float invB) {
  int j = threadIdx.x;  // 512
  float m0 = mom[0] * invB, m1 = mom[1] * invB, m2 = mom[2] * invB, m3 = mom[3] * invB;
  float C00 = mom[4]  * invB - m0 * m0, C01 = mom[5]  * invB - m0 * m1;
  float C02 = mom[6]  * invB - m0 * m2, C03 = mom[7]  * invB - m0 * m3;
  float C11 = mom[8]  * invB - m1 * m1, C12 = mom[9]  * invB - m1 * m2;
  float C13 = mom[10] * invB - m1 * m3, C22 = mom[11] * invB - m2 * m2;
  float C23 = mom[12] * invB - m2 * m3, C33 = mom[13] * invB - m3 * m3;
  float a = w1[j], b = w1[512 + j], c = w1[1024 + j], d = w1[1536 + j];
  float var = a * a * C00 + b * b * C11 + c * c * C22 + d * d * C33 +
              2.f * (a * b * C01 + a * c * C02 + a * d * C03 +
                     b * c * C12 + b * d * C13 + c * d * C23);
  float s1 = g1[j] * rsqrtf(fmaxf(var, 0.f) + 1e-5f) * TANH_PRESCALE;
  float a0 = a * s1, a1 = b * s1, a2 = c * s1, a3 = d * s1;
  float c1j = be1[j] * TANH_PRESCALE -
              (m0 * a + m1 * b + m2 * c + m3 * d) * s1;
  u16 ba0 = f2bf(a0), ba1 = f2bf(a1), ba2 = f2bf(a2), ba3 = f2bf(a3);
  u16 da0 = f2bf(a0 - bf2f(ba0)), da1 = f2bf(a1 - bf2f(ba1));
  u16 da2 = f2bf(a2 - bf2f(ba2)), da3 = f2bf(a3 - bf2f(ba3));
  u16 c1h = f2bf(c1j);
  u16 c1l = f2bf(c1j - bf2f(c1h));
  u32 p01 = (u32)ba0 | ((u32)ba1 << 16);
  u32 p23 = (u32)ba2 | ((u32)ba3 << 16);
  uint4* img = (uint4*)a1img;
  img[j * 2]     = make_uint4(p01, p23, (u32)c1h | ((u32)da0 << 16),
                              (u32)da1 | ((u32)da2 << 16));
  img[j * 2 + 1] = make_uint4(p01, p23, (u32)c1l | ((u32)da3 << 16), 0u);
}

// ---------- pass 1: fused t1 + GEMM(t1 @ w2), stats + fragment t2 dump ----------
// R8/R11 geometry: 1024 threads = 16 waves = 2(M) x 8(N); wave tile 64x64
// (2 mf x 2 nf, acc = 64 AGPR, ~4 waves/SIMD).
// NEW: deferred-write production. produce_compute at s==0 (MFMA+tanh+pack
// into 8 VGPRs; a1img load has 7 k-steps of latency cover); produce_write
// (8 ds_writes) at s==7, right before the slab barrier whose drain waits
// for them anyway. Steps 1..7 carry no pending LDS writes -> A-read
// lgkmcnt waits no longer serialize behind produce-write completion.
__global__ __launch_bounds__(1024) void gemm12_kernel(
    const float* __restrict__ x, const float* __restrict__ tsg,
    const float* __restrict__ teg, const float* __restrict__ tbg,
    const unsigned char* __restrict__ a1img,
    const unsigned char* __restrict__ w2ts, float* __restrict__ stat2,
    unsigned char* __restrict__ t2buf, int nstore) {
  __shared__ __align__(16) unsigned char sm_buf[2][32768];  // t1 slabs, chunk-major
  __shared__ __align__(16) float sm_u[128][4];
  __shared__ float sm_ts[9], sm_te[14], sm_tb[126];

  const int t = threadIdx.x;
  const int w = t >> 6, l = t & 63;
  const int hi = l >> 5, ln = l & 31;
  const int wm = w >> 3;         // consumer row-half (rows wm*64 .. +63)
  const int wn = w & 7;          // consumer col-block (cols wn*64 .. +63)
  const int rt = w & 3;          // production batch row-tile (rows rt*32..)
  const int jt = w >> 2;         // production j-tile (local 0..3)
  const int r0 = blockIdx.x * 128;

  if (t < 9) sm_ts[t] = tsg[t];
  if (t < 14) sm_te[t] = teg[t];
  if (t < 126) sm_tb[t] = tbg[t];
  __syncthreads();

  if (t < 128) {
    const float* xr = x + (size_t)(r0 + t) * 15;
    float amb = xr[1], inc = xr[8];
    sm_u[t][0] = inter2d_d(sm_ts, sm_te, sm_tb, xr[2], amb) - inc;
    sm_u[t][1] = inter2d_d(sm_ts, sm_te, sm_tb, xr[3], amb) - inc;
    sm_u[t][2] = amb;
    sm_u[t][3] = xr[9] - xr[10];
  }
  __syncthreads();

  // u B-frag for layer-1 MFMA: lane = batch row rt*32+ln.
  bf16x8 ufrag;
  {
    float4 uv = *(const float4*)&sm_u[rt * 32 + ln][0];
    u16 b0_ = f2bf(uv.x), b1_ = f2bf(uv.y), b2_ = f2bf(uv.z), b3_ = f2bf(uv.w);
    u32x4 uq;
    if (hi == 0) {
      uq[0] = (u32)b0_ | ((u32)b1_ << 16);
      uq[1] = (u32)b2_ | ((u32)b3_ << 16);
      uq[2] = 0x00003F80u | ((u32)b0_ << 16);
      uq[3] = (u32)b1_ | ((u32)b2_ << 16);
    } else {
      u16 d0 = f2bf(uv.x - bf2f(b0_)), d1 = f2bf(uv.y - bf2f(b1_));
      u16 d2 = f2bf(uv.z - bf2f(b2_)), d3 = f2bf(uv.w - bf2f(b3_));
      uq[0] = (u32)d0 | ((u32)d1 << 16);
      uq[1] = (u32)d2 | ((u32)d3 << 16);
      uq[2] = 0x00003F80u | ((u32)b3_ << 16);
      uq[3] = 0u;
    }
    ufrag = __builtin_bit_cast(bf16x8, uq);
  }

  // deferred-write production of the (rt, jt) 32x32 t1 tile of slab sl
  u32 pq[8];
  auto produce_compute = [&](int sl) {
    bf16x8 af = *(const bf16x8*)(a1img +
        ((size_t)(sl * 128 + jt * 32 + ln) * 32 + hi * 16));
    f32x16 z = {};
    f32x16 d = __builtin_amdgcn_mfma_f32_32x32x16_bf16(af, ufrag, z, 0, 0, 0);
#pragma unroll
    for (int q = 0; q < 4; ++q) {
      pq[q * 2]     = cvtpk_bf16(tanh_pre(d[q * 4 + 0]), tanh_pre(d[q * 4 + 1]));
      pq[q * 2 + 1] = cvtpk_bf16(tanh_pre(d[q * 4 + 2]), tanh_pre(d[q * 4 + 3]));
    }
  };
  auto produce_write = [&](int sl) {
    unsigned char* dst = sm_buf[sl & 1];
#pragma unroll
    for (int q = 0; q < 4; ++q)
      *(uint2*)(dst + ((size_t)((jt * 4 + q) * 128 + rt * 32 + ln) * 16 + hi * 8)) =
          make_uint2(pq[q * 2], pq[q * 2 + 1]);
  };

  // B frag loads: global K-octet G = ks*2 + hi; cols wn*64 + nf*32 + ln
  auto loadB = [&](uint4* dst, int ks) {
    const unsigned char* p = w2ts + ((size_t)(ks * 2 + hi) * 8192) +
                             (size_t)(wn * 64 + ln) * 16;
    dst[0] = *(const uint4*)(p);
    dst[1] = *(const uint4*)(p + 512);
  };

  f32x16 acc[4];  // [mf*2+nf]
#pragma unroll
  for (int i = 0; i < 4; ++i)
#pragma unroll
    for (int k = 0; k < 16; ++k) acc[i][k] = 0.0f;

  uint4 bb[2][2];
  loadB(bb[0], 0);
  produce_compute(0);
  produce_write(0);
  __syncthreads();

#pragma unroll
  for (int sl = 0; sl < 4; ++sl) {
    const unsigned char* abuf = sm_buf[sl & 1];
#pragma unroll
    for (int s = 0; s < 8; ++s) {
      int ks = sl * 8 + s;
      if (ks < 31) loadB(bb[(ks + 1) & 1], ks + 1);
      const unsigned char* ab =
          abuf + ((size_t)(2 * s + hi) * 128 + wm * 64 + ln) * 16;
      bf16x8 a0 = *(const bf16x8*)(ab);
      bf16x8 a1 = *(const bf16x8*)(ab + 512);
#pragma unroll
      for (int nf = 0; nf < 2; ++nf) {
        bf16x8 bv = __builtin_bit_cast(bf16x8, bb[ks & 1][nf]);
        acc[0 + nf] = __builtin_amdgcn_mfma_f32_32x32x16_bf16(a0, bv, acc[0 + nf], 0, 0, 0);
        acc[2 + nf] = __builtin_amdgcn_mfma_f32_32x32x16_bf16(a1, bv, acc[2 + nf], 0, 0, 0);
      }
      if (sl < 3) {
        if (s == 0) produce_compute(sl + 1);
        if (s == 7) produce_write(sl + 1);
      }
    }
    __syncthreads();
  }

  // C/D layout (32x32x16): col = lane&31, row_in_tile = (k&3) + 8*(k>>2) + 4*hi
  if (blockIdx.x < (u32)nstore) {
    // fp16 t2 fragments, [chunk][tid] interleave (coalesced 16B stores)
    uint4* dst = (uint4*)(t2buf + (size_t)blockIdx.x * 131072);
#pragma unroll
    for (int i = 0; i < 4; ++i)
#pragma unroll
      for (int h2 = 0; h2 < 2; ++h2) {
        uint4 pk4;
        pk4.x = packf16(acc[i][h2 * 8 + 0], acc[i][h2 * 8 + 1]);
        pk4.y = packf16(acc[i][h2 * 8 + 2], acc[i][h2 * 8 + 3]);
        pk4.z = packf16(acc[i][h2 * 8 + 4], acc[i][h2 * 8 + 5]);
        pk4.w = packf16(acc[i][h2 * 8 + 6], acc[i][h2 * 8 + 7]);
        dst[(i * 2 + h2) * 1024 + t] = pk4;
      }
  }
  // column sums: wave covers rows wm*64..+63 for cols wn*64+nf*32+ln;
  // both wm halves atomically add (covers all 128 rows).
#pragma unroll
  for (int nf = 0; nf < 2; ++nf) {
    float s = 0.f, q = 0.f;
#pragma unroll
    for (int mf = 0; mf < 2; ++mf)
#pragma unroll
      for (int k = 0; k < 16; ++k) {
        float v = acc[mf * 2 + nf][k];
        s += v; q += v * v;
      }
    s += __shfl_xor(s, 32); q += __shfl_xor(q, 32);
    if (hi == 0) {
      int col = wn * 64 + nf * 32 + ln;
      atomicAdd(&stat2[col], s);
      atomicAdd(&stat2[512 + col], q);
    }
  }
}

// ---------- pass 2a: readback stored tiles (grid = nstore) ----------
__global__ __launch_bounds__(1024) void finish_rb(
    const float* __restrict__ stat2,
    const unsigned char* __restrict__ t2buf,
    const float* __restrict__ g2, const float* __restrict__ be2,
    const float* __restrict__ w3g, const float* __restrict__ b3g,
    float* __restrict__ out, float invB) {
  __shared__ float pr[128 * 8];
  const int t = threadIdx.x;
  const int w = t >> 6, l = t & 63;
  const int hi = l >> 5, ln = l & 31;
  const int wm = w >> 3, wn = w & 7;
  const int r0 = blockIdx.x * 128;

  float sv[2], cv[2], wv[2];
#pragma unroll
  for (int nf = 0; nf < 2; ++nf) {
    int col = wn * 64 + nf * 32 + ln;
    float mu = stat2[col] * invB;
    float ex2 = stat2[512 + col] * invB;
    float var = fmaxf(ex2 - mu * mu, 0.f);
    float s = g2[col] * rsqrtf(var + 1e-5f);
    sv[nf] = s * TANH_PRESCALE;
    cv[nf] = (be2[col] - mu * s) * TANH_PRESCALE;
    wv[nf] = w3g[col];
  }
  const uint4* src = (const uint4*)(t2buf + (size_t)blockIdx.x * 131072);
#pragma unroll
  for (int mf = 0; mf < 2; ++mf) {
    uint4 q[2][2];
#pragma unroll
    for (int nf = 0; nf < 2; ++nf)
#pragma unroll
      for (int h2 = 0; h2 < 2; ++h2)
        q[nf][h2] = src[((mf * 2 + nf) * 2 + h2) * 1024 + t];
#pragma unroll
    for (int k = 0; k < 16; ++k) {
      float v = 0.f;
#pragma unroll
      for (int nf = 0; nf < 2; ++nf) {
        f16x8 qq = __builtin_bit_cast(f16x8, q[nf][k >> 3]);
        float a0 = (float)qq[k & 7];
        v += tanh_pre(a0 * sv[nf] + cv[nf]) * wv[nf];
      }
      v += __shfl_xor(v, 1); v += __shfl_xor(v, 2); v += __shfl_xor(v, 4);
      v += __shfl_xor(v, 8); v += __shfl_xor(v, 16);
      if (ln == 0) {
        int row = wm * 64 + mf * 32 + (k & 3) + 8 * (k >> 2) + 4 * hi;
        pr[row * 8 + wn] = v;
      }
    }
  }
  __syncthreads();
  if (t < 128) {
    float s = b3g[0];
#pragma unroll
    for (int i = 0; i < 8; ++i) s += pr[t * 8 + i];
    out[r0 + t] = s;
  }
}

// ---------- pass 2b: recompute tiles (grid = ntiles - nstore, offset blk0) ----------
__global__ __launch_bounds__(1024) void finish_rc(
    const float* __restrict__ x, const float* __restrict__ tsg,
    const float* __restrict__ teg, const float* __restrict__ tbg,
    const unsigned char* __restrict__ a1img,
    const unsigned char* __restrict__ w2ts,
    const float* __restrict__ stat2,
    const float* __restrict__ g2, const float* __restrict__ be2,
    const float* __restrict__ w3g, const float* __restrict__ b3g,
    float* __restrict__ out, int blk0, float invB) {
  __shared__ __align__(16) unsigned char sm_buf[2][32768];
  __shared__ __align__(16) float sm_u[128][4];
  __shared__ float sm_ts[9], sm_te[14], sm_tb[126];

  const int t = threadIdx.x;
  const int w = t >> 6, l = t & 63;
  const int hi = l >> 5, ln = l & 31;
  const int wm = w >> 3;
  const int wn = w & 7;
  const int rt = w & 3;
  const int jt = w >> 2;
  const int r0 = (blockIdx.x + blk0) * 128;

  float sv[2], cv[2], wv[2];
#pragma unroll
  for (int nf = 0; nf < 2; ++nf) {
    int col = wn * 64 + nf * 32 + ln;
    float mu = stat2[col] * invB;
    float ex2 = stat2[512 + col] * invB;
    float var = fmaxf(ex2 - mu * mu, 0.f);
    float s = g2[col] * rsqrtf(var + 1e-5f);
    sv[nf] = s * TANH_PRESCALE;
    cv[nf] = (be2[col] - mu * s) * TANH_PRESCALE;
    wv[nf] = w3g[col];
  }

  if (t < 9) sm_ts[t] = tsg[t];
  if (t < 14) sm_te[t] = teg[t];
  if (t < 126) sm_tb[t] = tbg[t];
  __syncthreads();

  if (t < 128) {
    const float* xr = x + (size_t)(r0 + t) * 15;
    float amb = xr[1], inc = xr[8];
    sm_u[t][0] = inter2d_d(sm_ts, sm_te, sm_tb, xr[2], amb) - inc;
    sm_u[t][1] = inter2d_d(sm_ts, sm_te, sm_tb, xr[3], amb) - inc;
    sm_u[t][2] = amb;
    sm_u[t][3] = xr[9] - xr[10];
  }
  __syncthreads();

  bf16x8 ufrag;
  {
    float4 uv = *(const float4*)&sm_u[rt * 32 + ln][0];
    u16 b0_ = f2bf(uv.x), b1_ = f2bf(uv.y), b2_ = f2bf(uv.z), b3_ = f2bf(uv.w);
    u32x4 uq;
    if (hi == 0) {
      uq[0] = (u32)b0_ | ((u32)b1_ << 16);
      uq[1] = (u32)b2_ | ((u32)b3_ << 16);
      uq[2] = 0x00003F80u | ((u32)b0_ << 16);
      uq[3] = (u32)b1_ | ((u32)b2_ << 16);
    } else {
      u16 d0 = f2bf(uv.x - bf2f(b0_)), d1 = f2bf(uv.y - bf2f(b1_));
      u16 d2 = f2bf(uv.z - bf2f(b2_)), d3 = f2bf(uv.w - bf2f(b3_));
      uq[0] = (u32)d0 | ((u32)d1 << 16);
      uq[1] = (u32)d2 | ((u32)d3 << 16);
      uq[2] = 0x00003F80u | ((u32)b3_ << 16);
      uq[3] = 0u;
    }
    ufrag = __builtin_bit_cast(bf16x8, uq);
  }

  u32 pq[8];
  auto produce_compute = [&](int sl) {
    bf16x8 af = *(const bf16x8*)(a1img +
        ((size_t)(sl * 128 + jt * 32 + ln) * 32 + hi * 16));
    f32x16 z = {};
    f32x16 d = __builtin_amdgcn_mfma_f32_32x32x16_bf16(af, ufrag, z, 0, 0, 0);
#pragma unroll
    for (int q = 0; q < 4; ++q) {
      pq[q * 2]     = cvtpk_bf16(tanh_pre(d[q * 4 + 0]), tanh_pre(d[q * 4 + 1]));
      pq[q * 2 + 1] = cvtpk_bf16(tanh_pre(d[q * 4 + 2]), tanh_pre(d[q * 4 + 3]));
    }
  };
  auto produce_write = [&](int sl) {
    unsigned char* dst = sm_buf[sl & 1];
#pragma unroll
    for (int q = 0; q < 4; ++q)
      *(uint2*)(dst + ((size_t)((jt * 4 + q) * 128 + rt * 32 + ln) * 16 + hi * 8)) =
          make_uint2(pq[q * 2], pq[q * 2 + 1]);
  };

  auto loadB = [&](uint4* dst, int ks) {
    const unsigned char* p = w2ts + ((size_t)(ks * 2 + hi) * 8192) +
                             (size_t)(wn * 64 + ln) * 16;
    dst[0] = *(const uint4*)(p);
    dst[1] = *(const uint4*)(p + 512);
  };

  f32x16 acc[4];
#pragma unroll
  for (int i = 0; i < 4; ++i)
#pragma unroll
    for (int k = 0; k < 16; ++k) acc[i][k] = 0.0f;

  uint4 bb[2][2];
  loadB(bb[0], 0);
  produce_compute(0);
  produce_write(0);
  __syncthreads();

#pragma unroll
  for (int sl = 0; sl < 4; ++sl) {
    const unsigned char* abuf = sm_buf[sl & 1];
#pragma unroll
    for (int s = 0; s < 8; ++s) {
      int ks = sl * 8 + s;
      if (ks < 31) loadB(bb[(ks + 1) & 1], ks + 1);
      const unsigned char* ab =
          abuf + ((size_t)(2 * s + hi) * 128 + wm * 64 + ln) * 16;
      bf16x8 a0 = *(const bf16x8*)(ab);
      bf16x8 a1 = *(const bf16x8*)(ab + 512);
#pragma unroll
      for (int nf = 0; nf < 2; ++nf) {
        bf16x8 bv = __builtin_bit_cast(bf16x8, bb[ks & 1][nf]);
        acc[0 + nf] = __builtin_amdgcn_mfma_f32_32x32x16_bf16(a0, bv, acc[0 + nf], 0, 0, 0);
        acc[2 + nf] = __builtin_amdgcn_mfma_f32_32x32x16_bf16(a1, bv, acc[2 + nf], 0, 0, 0);
      }
      if (sl < 3) {
        if (s == 0) produce_compute(sl + 1);
        if (s == 7) produce_write(sl + 1);
      }
    }
    __syncthreads();
  }

  float* pr = (float*)sm_buf[0];  // [128 rows][8 col-blocks]
#pragma unroll
  for (int mf = 0; mf < 2; ++mf)
#pragma unroll
    for (int k = 0; k < 16; ++k) {
      float v = tanh_pre(acc[mf * 2 + 0][k] * sv[0] + cv[0]) * wv[0] +
                tanh_pre(acc[mf * 2 + 1][k] * sv[1] + cv[1]) * wv[1];
      v += __shfl_xor(v, 1); v += __shfl_xor(v, 2); v += __shfl_xor(v, 4);
      v += __shfl_xor(v, 8); v += __shfl_xor(v, 16);
      if (ln == 0) {
        int row = wm * 64 + mf * 32 + (k & 3) + 8 * (k >> 2) + 4 * hi;
        pr[row * 8 + wn] = v;
      }
    }
  __syncthreads();
  if (t < 128) {
    float s = b3g[0];
#pragma unroll
    for (int i = 0; i < 8; ++i) s += pr[t * 8 + i];
    out[r0 + t] = s;
  }
}

// ---------- launcher ----------
extern "C" void kernel_launch(void* const* d_in, const int* in_sizes, int n_in,
                              void* d_out, int out_size, void* d_ws, size_t ws_size,
                              hipStream_t stream) {
  const float* x   = (const float*)d_in[0];
  const float* ts  = (const float*)d_in[1];
  const float* te  = (const float*)d_in[2];
  const float* tab = (const float*)d_in[3];
  const float* w1  = (const float*)d_in[4];
  const float* g1  = (const float*)d_in[6];
  const float* be1 = (const float*)d_in[7];
  const float* w2  = (const float*)d_in[8];
  const float* g2  = (const float*)d_in[10];
  const float* be2 = (const float*)d_in[11];
  const float* w3  = (const float*)d_in[12];
  const float* b3  = (const float*)d_in[13];
  float* out = (float*)d_out;
  char* ws = (char*)d_ws;

  if (ws_size < (size_t)(32768 + 524288)) return;

  int Bn = in_sizes[0] / 15;  // 262144
  float invB = 1.0f / (float)Bn;
  int ntiles = Bn / 128;      // 2048
  int nstat = Bn / 256;       // 1024

  float* mom   = (float*)(ws + 0);      // 14 f32 (zeroed)
  float* stat2 = (float*)(ws + 64);     // 1024 f32 (zeroed)
  unsigned char* a1img = (unsigned char*)(ws + 4160);  // 16 KB (512 j x 32B)
  unsigned char* w2ts = (unsigned char*)(ws + 32768);  // 512 KB bf16 image
  unsigned char* t2buf = (unsigned char*)(ws + (1 << 20));  // fp16 t2 (adaptive)

  // adaptive: store as many 128-row t2 tiles (128*512*2 = 128 KB each) as fit
  size_t avail = ws_size > (size_t)(1 << 20) ? ws_size - (size_t)(1 << 20) : 0;
  size_t cap = avail / 131072;
  int nstore = cap >= (size_t)ntiles ? ntiles : (int)cap;

  (void)hipMemsetAsync(ws, 0, 4160, stream);
  pre_kernel<<<nstat + 128, 256, 0, stream>>>(x, ts, te, tab, mom, w2, w2ts, nstat);
  prep1_kernel<<<1, 512, 0, stream>>>(mom, w1, g1, be1, a1img, invB);
  gemm12_kernel<<<ntiles, 1024, 0, stream>>>(x, ts, te, tab, a1img, w2ts,
                                             stat2, t2buf, nstore);
  if (nstore > 0)
    finish_rb<<<nstore, 1024, 0, stream>>>(stat2, t2buf, g2, be2, w3, b3,
                                           out, invB);
  if (nstore < ntiles)
    finish_rc<<<ntiles - nstore, 1024, 0, stream>>>(
        x, ts, te, tab, a1img, w2ts, stat2, g2, be2, w3, b3, out,
        nstore, invB);
}

// Round 16
// 369.448 us; speedup vs baseline: 1.1336x; 1.1152x over previous
//
#include <hip/hip_runtime.h>

typedef unsigned int u32;
typedef unsigned short u16;
typedef __bf16 bf16x8 __attribute__((ext_vector_type(8)));
typedef float f32x16 __attribute__((ext_vector_type(16)));
typedef u32 u32x4 __attribute__((ext_vector_type(4)));
typedef _Float16 f16x2 __attribute__((ext_vector_type(2)));
typedef _Float16 f16x8 __attribute__((ext_vector_type(8)));

// K = 2*log2(e): folded into the layer-1 A-image and the BN2 scale/bias so
// tanh(x) = 1 - 2/(exp2(K*x)+1) needs zero multiplies at eval time.
#define TANH_PRESCALE 2.8853900817779268f
// per-tile t2 storage: 64 KB int8 fragments + 2 KB f16 per-thread scales
#define T2_TILE_BYTES 67584

// ---------- helpers ----------
__device__ __forceinline__ u16 f2bf(float f) {
  u32 u = __float_as_uint(f);
  u32 r = (u + 0x7FFFu + ((u >> 16) & 1u)) >> 16;
  return (u16)r;
}
__device__ __forceinline__ float bf2f(u16 h) {
  return __uint_as_float((u32)h << 16);
}
// single-instruction RNE bf16 pack (same rounding as f2bf)
__device__ __forceinline__ u32 cvtpk_bf16(float a, float b) {
  u32 r;
  asm("v_cvt_pk_bf16_f32 %0, %1, %2" : "=v"(r) : "v"(a), "v"(b));
  return r;
}
// tanh of x where v = TANH_PRESCALE * x has been pre-folded upstream
__device__ __forceinline__ float tanh_pre(float v) {
  float e = __builtin_exp2f(v);
  return 1.0f - 2.0f * __builtin_amdgcn_rcpf(e + 1.0f);
}

// bilinear interp matching jnp.searchsorted(side='right')-1 with clamping
__device__ __forceinline__ float inter2d_d(const float* xs, const float* ys,
                                           const float* tb, float xq, float yq) {
  xq = fminf(fmaxf(xq, xs[0]), xs[8]);
  yq = fminf(fmaxf(yq, ys[0]), ys[13]);
  int i = 0, j = 0;
#pragma unroll
  for (int k = 1; k <= 8; ++k) if (xq >= xs[k]) i = k;
#pragma unroll
  for (int k = 1; k <= 13; ++k) if (yq >= ys[k]) j = k;
  if (i > 7) i = 7;
  if (j > 12) j = 12;
  float x0 = xs[i], x1 = xs[i + 1], y0 = ys[j], y1 = ys[j + 1];
  float tx = (xq - x0) / (x1 - x0);
  float ty = (yq - y0) / (y1 - y0);
  float f00 = tb[i * 14 + j], f01 = tb[i * 14 + j + 1];
  float f10 = tb[(i + 1) * 14 + j], f11 = tb[(i + 1) * 14 + j + 1];
  return f00 * (1 - tx) * (1 - ty) + f10 * tx * (1 - ty) +
         f01 * (1 - tx) * ty + f11 * tx * ty;
}

// ---------- kernel 1: merged u-moments (blocks < nstat) + w2 transpose ----------
__global__ void pre_kernel(const float* __restrict__ x,
                           const float* __restrict__ tsg,
                           const float* __restrict__ teg,
                           const float* __restrict__ tbg,
                           float* __restrict__ mom,
                           const float* __restrict__ w2,
                           unsigned char* __restrict__ w2ts, int nstat) {
  __shared__ float ts[9], te[14], tb[126], bacc[14];
  int t = threadIdx.x;
  if ((int)blockIdx.x >= nstat) {
    int q = ((int)blockIdx.x - nstat) * 256 + t;  // 0..32767
    int n = q & 511;
    int kb = (q >> 9) * 8;
    u32 pk[4];
#pragma unroll
    for (int e = 0; e < 8; e += 2) {
      u16 a = f2bf(w2[(size_t)(kb + e) * 512 + n]);
      u16 b = f2bf(w2[(size_t)(kb + e + 1) * 512 + n]);
      pk[e >> 1] = (u32)a | ((u32)b << 16);
    }
    *(uint4*)(w2ts + (size_t)q * 16) = make_uint4(pk[0], pk[1], pk[2], pk[3]);
    return;
  }
  if (t < 9) ts[t] = tsg[t];
  if (t < 14) { te[t] = teg[t]; bacc[t] = 0.f; }
  if (t < 126) tb[t] = tbg[t];
  __syncthreads();
  const float* xr = x + (size_t)(blockIdx.x * 256 + t) * 15;
  float amb = xr[1], inc = xr[8];
  float u0 = inter2d_d(ts, te, tb, xr[2], amb) - inc;
  float u1 = inter2d_d(ts, te, tb, xr[3], amb) - inc;
  float u2 = amb, u3 = xr[9] - xr[10];
  float v[14] = {u0, u1, u2, u3,
                 u0 * u0, u0 * u1, u0 * u2, u0 * u3,
                 u1 * u1, u1 * u2, u1 * u3,
                 u2 * u2, u2 * u3, u3 * u3};
#pragma unroll
  for (int i = 0; i < 14; ++i) {
    float s = v[i];
    s += __shfl_xor(s, 32); s += __shfl_xor(s, 16); s += __shfl_xor(s, 8);
    s += __shfl_xor(s, 4);  s += __shfl_xor(s, 2);  s += __shfl_xor(s, 1);
    v[i] = s;
  }
  if ((t & 63) == 0)
    for (int i = 0; i < 14; ++i) atomicAdd(&bacc[i], v[i]);
  __syncthreads();
  if (t < 14) atomicAdd(&mom[t], bacc[t]);
}

// ---------- kernel 2: fold BN1 (and tanh prescale) into layer-1 A-image ----------
__global__ void prep1_kernel(const float* __restrict__ mom,
                             const float* __restrict__ w1,
                             const float* __restrict__ g1,
                             const float* __restrict__ be1,
                             unsigned char* __restrict__ a1img, float invB) {
  int j = threadIdx.x;  // 512
  float m0 = mom[0] * invB, m1 = mom[1] * invB, m2 = mom[2] * invB, m3 = mom[3] * invB;
  float C00 = mom[4]  * invB - m0 * m0, C01 = mom[5]  * invB - m0 * m1;
  float C02 = mom[6]  * invB - m0 * m2, C03 = mom[7]  * invB - m0 * m3;
  float C11 = mom[8]  * invB - m1 * m1, C12 = mom[9]  * invB - m1 * m2;
  float C13 = mom[10] * invB - m1 * m3, C22 = mom[11] * invB - m2 * m2;
  float C23 = mom[12] * invB - m2 * m3, C33 = mom[13] * invB - m3 * m3;
  float a = w1[j], b = w1[512 + j], c = w1[1024 + j], d = w1[1536 + j];
  float var = a * a * C00 + b * b * C11 + c * c * C22 + d * d * C33 +
              2.f * (a * b * C01 + a * c * C02 + a * d * C03 +
                     b * c * C12 + b * d * C13 + c * d * C23);
  float s1 = g1[j] * rsqrtf(fmaxf(var, 0.f) + 1e-5f) * TANH_PRESCALE;
  float a0 = a * s1, a1 = b * s1, a2 = c * s1, a3 = d * s1;
  float c1j = be1[j] * TANH_PRESCALE -
              (m0 * a + m1 * b + m2 * c + m3 * d) * s1;
  u16 ba0 = f2bf(a0), ba1 = f2bf(a1), ba2 = f2bf(a2), ba3 = f2bf(a3);
  u16 da0 = f2bf(a0 - bf2f(ba0)), da1 = f2bf(a1 - bf2f(ba1));
  u16 da2 = f2bf(a2 - bf2f(ba2)), da3 = f2bf(a3 - bf2f(ba3));
  u16 c1h = f2bf(c1j);
  u16 c1l = f2bf(c1j - bf2f(c1h));
  u32 p01 = (u32)ba0 | ((u32)ba1 << 16);
  u32 p23 = (u32)ba2 | ((u32)ba3 << 16);
  uint4* img = (uint4*)a1img;
  img[j * 2]     = make_uint4(p01, p23, (u32)c1h | ((u32)da0 << 16),
                              (u32)da1 | ((u32)da2 << 16));
  img[j * 2 + 1] = make_uint4(p01, p23, (u32)c1l | ((u32)da3 << 16), 0u);
}

// ---------- pass 1: fused t1 + GEMM(t1 @ w2), stats + int8 t2 dump ----------
// R8/R11/R15 geometry: 1024 threads = 16 waves = 2(M) x 8(N); wave tile
// 64x64 (2 mf x 2 nf, acc = 64 AGPR, ~4 waves/SIMD). Blocks < nstore store
// int8-quantized t2 fragments (one f16 scale per thread over its 64 values)
// -> 66 KB/tile vs fp16's 128 KB: ~1.94x more tiles fit in the workspace,
// shrinking the pass-2 recompute fraction toward zero.
__global__ __launch_bounds__(1024) void gemm12_kernel(
    const float* __restrict__ x, const float* __restrict__ tsg,
    const float* __restrict__ teg, const float* __restrict__ tbg,
    const unsigned char* __restrict__ a1img,
    const unsigned char* __restrict__ w2ts, float* __restrict__ stat2,
    unsigned char* __restrict__ t2buf, int nstore) {
  __shared__ __align__(16) unsigned char sm_buf[2][32768];  // t1 slabs, chunk-major
  __shared__ __align__(16) float sm_u[128][4];
  __shared__ float sm_ts[9], sm_te[14], sm_tb[126];

  const int t = threadIdx.x;
  const int w = t >> 6, l = t & 63;
  const int hi = l >> 5, ln = l & 31;
  const int wm = w >> 3;         // consumer row-half (rows wm*64 .. +63)
  const int wn = w & 7;          // consumer col-block (cols wn*64 .. +63)
  const int rt = w & 3;          // production batch row-tile (rows rt*32..)
  const int jt = w >> 2;         // production j-tile (local 0..3)
  const int r0 = blockIdx.x * 128;

  if (t < 9) sm_ts[t] = tsg[t];
  if (t < 14) sm_te[t] = teg[t];
  if (t < 126) sm_tb[t] = tbg[t];
  __syncthreads();

  if (t < 128) {
    const float* xr = x + (size_t)(r0 + t) * 15;
    float amb = xr[1], inc = xr[8];
    sm_u[t][0] = inter2d_d(sm_ts, sm_te, sm_tb, xr[2], amb) - inc;
    sm_u[t][1] = inter2d_d(sm_ts, sm_te, sm_tb, xr[3], amb) - inc;
    sm_u[t][2] = amb;
    sm_u[t][3] = xr[9] - xr[10];
  }
  __syncthreads();

  // u B-frag for layer-1 MFMA: lane = batch row rt*32+ln.
  bf16x8 ufrag;
  {
    float4 uv = *(const float4*)&sm_u[rt * 32 + ln][0];
    u16 b0_ = f2bf(uv.x), b1_ = f2bf(uv.y), b2_ = f2bf(uv.z), b3_ = f2bf(uv.w);
    u32x4 uq;
    if (hi == 0) {
      uq[0] = (u32)b0_ | ((u32)b1_ << 16);
      uq[1] = (u32)b2_ | ((u32)b3_ << 16);
      uq[2] = 0x00003F80u | ((u32)b0_ << 16);
      uq[3] = (u32)b1_ | ((u32)b2_ << 16);
    } else {
      u16 d0 = f2bf(uv.x - bf2f(b0_)), d1 = f2bf(uv.y - bf2f(b1_));
      u16 d2 = f2bf(uv.z - bf2f(b2_)), d3 = f2bf(uv.w - bf2f(b3_));
      uq[0] = (u32)d0 | ((u32)d1 << 16);
      uq[1] = (u32)d2 | ((u32)d3 << 16);
      uq[2] = 0x00003F80u | ((u32)b3_ << 16);
      uq[3] = 0u;
    }
    ufrag = __builtin_bit_cast(bf16x8, uq);
  }

  // deferred-write production of the (rt, jt) 32x32 t1 tile of slab sl
  u32 pq[8];
  auto produce_compute = [&](int sl) {
    bf16x8 af = *(const bf16x8*)(a1img +
        ((size_t)(sl * 128 + jt * 32 + ln) * 32 + hi * 16));
    f32x16 z = {};
    f32x16 d = __builtin_amdgcn_mfma_f32_32x32x16_bf16(af, ufrag, z, 0, 0, 0);
#pragma unroll
    for (int q = 0; q < 4; ++q) {
      pq[q * 2]     = cvtpk_bf16(tanh_pre(d[q * 4 + 0]), tanh_pre(d[q * 4 + 1]));
      pq[q * 2 + 1] = cvtpk_bf16(tanh_pre(d[q * 4 + 2]), tanh_pre(d[q * 4 + 3]));
    }
  };
  auto produce_write = [&](int sl) {
    unsigned char* dst = sm_buf[sl & 1];
#pragma unroll
    for (int q = 0; q < 4; ++q)
      *(uint2*)(dst + ((size_t)((jt * 4 + q) * 128 + rt * 32 + ln) * 16 + hi * 8)) =
          make_uint2(pq[q * 2], pq[q * 2 + 1]);
  };

  // B frag loads: global K-octet G = ks*2 + hi; cols wn*64 + nf*32 + ln
  auto loadB = [&](uint4* dst, int ks) {
    const unsigned char* p = w2ts + ((size_t)(ks * 2 + hi) * 8192) +
                             (size_t)(wn * 64 + ln) * 16;
    dst[0] = *(const uint4*)(p);
    dst[1] = *(const uint4*)(p + 512);
  };

  f32x16 acc[4];  // [mf*2+nf]
#pragma unroll
  for (int i = 0; i < 4; ++i)
#pragma unroll
    for (int k = 0; k < 16; ++k) acc[i][k] = 0.0f;

  uint4 bb[2][2];
  loadB(bb[0], 0);
  produce_compute(0);
  produce_write(0);
  __syncthreads();

#pragma unroll
  for (int sl = 0; sl < 4; ++sl) {
    const unsigned char* abuf = sm_buf[sl & 1];
#pragma unroll
    for (int s = 0; s < 8; ++s) {
      int ks = sl * 8 + s;
      if (ks < 31) loadB(bb[(ks + 1) & 1], ks + 1);
      const unsigned char* ab =
          abuf + ((size_t)(2 * s + hi) * 128 + wm * 64 + ln) * 16;
      bf16x8 a0 = *(const bf16x8*)(ab);
      bf16x8 a1 = *(const bf16x8*)(ab + 512);
#pragma unroll
      for (int nf = 0; nf < 2; ++nf) {
        bf16x8 bv = __builtin_bit_cast(bf16x8, bb[ks & 1][nf]);
        acc[0 + nf] = __builtin_amdgcn_mfma_f32_32x32x16_bf16(a0, bv, acc[0 + nf], 0, 0, 0);
        acc[2 + nf] = __builtin_amdgcn_mfma_f32_32x32x16_bf16(a1, bv, acc[2 + nf], 0, 0, 0);
      }
      if (sl < 3) {
        if (s == 0) produce_compute(sl + 1);
        if (s == 7) produce_write(sl + 1);
      }
    }
    __syncthreads();
  }

  // C/D layout (32x32x16): col = lane&31, row_in_tile = (k&3) + 8*(k>>2) + 4*hi
  if (blockIdx.x < (u32)nstore) {
    // int8 t2 fragments: one scale per thread over its 64 acc values.
    // chunk p = mf*2+nf holds the 16 k-values as bytes (word k>>2, byte k&3).
    float am = 0.f;
#pragma unroll
    for (int i = 0; i < 4; ++i)
#pragma unroll
      for (int k = 0; k < 16; ++k) am = fmaxf(am, fabsf(acc[i][k]));
    float inv = 127.0f / fmaxf(am, 1e-30f);
    unsigned char* tb8 = t2buf + (size_t)blockIdx.x * T2_TILE_BYTES;
    uint4* dst = (uint4*)tb8;
#pragma unroll
    for (int i = 0; i < 4; ++i) {
      u32 wd[4];
#pragma unroll
      for (int w4 = 0; w4 < 4; ++w4) {
        u32 b = 0;
#pragma unroll
        for (int j = 0; j < 4; ++j) {
          int q8 = (int)rintf(acc[i][w4 * 4 + j] * inv);
          b |= ((u32)(q8 & 0xFF)) << (8 * j);
        }
        wd[w4] = b;
      }
      dst[i * 1024 + t] = make_uint4(wd[0], wd[1], wd[2], wd[3]);
    }
    _Float16 sh = (_Float16)(am * (1.0f / 127.0f));
    *(u16*)(tb8 + 65536 + t * 2) = __builtin_bit_cast(u16, sh);
  }
  // column sums: wave covers rows wm*64..+63 for cols wn*64+nf*32+ln;
  // both wm halves atomically add (covers all 128 rows).
#pragma unroll
  for (int nf = 0; nf < 2; ++nf) {
    float s = 0.f, q = 0.f;
#pragma unroll
    for (int mf = 0; mf < 2; ++mf)
#pragma unroll
      for (int k = 0; k < 16; ++k) {
        float v = acc[mf * 2 + nf][k];
        s += v; q += v * v;
      }
    s += __shfl_xor(s, 32); q += __shfl_xor(q, 32);
    if (hi == 0) {
      int col = wn * 64 + nf * 32 + ln;
      atomicAdd(&stat2[col], s);
      atomicAdd(&stat2[512 + col], q);
    }
  }
}

// ---------- pass 2a: readback stored tiles (grid = nstore) ----------
// int8 dequant (same per-thread fragment mapping as the writer), then the
// proven R11/R15 epilogue: tanh, 5-level shfl reduce into pr, 8-way sum.
__global__ __launch_bounds__(1024) void finish_rb(
    const float* __restrict__ stat2,
    const unsigned char* __restrict__ t2buf,
    const float* __restrict__ g2, const float* __restrict__ be2,
    const float* __restrict__ w3g, const float* __restrict__ b3g,
    float* __restrict__ out, float invB) {
  __shared__ float pr[128 * 8];
  const int t = threadIdx.x;
  const int w = t >> 6, l = t & 63;
  const int hi = l >> 5, ln = l & 31;
  const int wm = w >> 3, wn = w & 7;
  const int r0 = blockIdx.x * 128;

  float sv[2], cv[2], wv[2];
#pragma unroll
  for (int nf = 0; nf < 2; ++nf) {
    int col = wn * 64 + nf * 32 + ln;
    float mu = stat2[col] * invB;
    float ex2 = stat2[512 + col] * invB;
    float var = fmaxf(ex2 - mu * mu, 0.f);
    float s = g2[col] * rsqrtf(var + 1e-5f);
    sv[nf] = s * TANH_PRESCALE;
    cv[nf] = (be2[col] - mu * s) * TANH_PRESCALE;
    wv[nf] = w3g[col];
  }
  const unsigned char* tb8 = t2buf + (size_t)blockIdx.x * T2_TILE_BYTES;
  const uint4* src = (const uint4*)tb8;
  uint4 ib[4];
#pragma unroll
  for (int p = 0; p < 4; ++p) ib[p] = src[p * 1024 + t];
  u16 sb = *(const u16*)(tb8 + 65536 + t * 2);
  float sc = (float)__builtin_bit_cast(_Float16, sb);

#pragma unroll
  for (int mf = 0; mf < 2; ++mf) {
#pragma unroll
    for (int k = 0; k < 16; ++k) {
      float v = 0.f;
#pragma unroll
      for (int nf = 0; nf < 2; ++nf) {
        int p = mf * 2 + nf;
        u32 word = (&ib[p].x)[k >> 2];
        int q8 = (int)(char)((word >> (8 * (k & 3))) & 0xFFu);
        float a0 = (float)q8 * sc;
        v += tanh_pre(a0 * sv[nf] + cv[nf]) * wv[nf];
      }
      v += __shfl_xor(v, 1); v += __shfl_xor(v, 2); v += __shfl_xor(v, 4);
      v += __shfl_xor(v, 8); v += __shfl_xor(v, 16);
      if (ln == 0) {
        int row = wm * 64 + mf * 32 + (k & 3) + 8 * (k >> 2) + 4 * hi;
        pr[row * 8 + wn] = v;
      }
    }
  }
  __syncthreads();
  if (t < 128) {
    float s = b3g[0];
#pragma unroll
    for (int i = 0; i < 8; ++i) s += pr[t * 8 + i];
    out[r0 + t] = s;
  }
}

// ---------- pass 2b: recompute tiles (grid = ntiles - nstore, offset blk0) ----------
__global__ __launch_bounds__(1024) void finish_rc(
    const float* __restrict__ x, const float* __restrict__ tsg,
    const float* __restrict__ teg, const float* __restrict__ tbg,
    const unsigned char* __restrict__ a1img,
    const unsigned char* __restrict__ w2ts,
    const float* __restrict__ stat2,
    const float* __restrict__ g2, const float* __restrict__ be2,
    const float* __restrict__ w3g, const float* __restrict__ b3g,
    float* __restrict__ out, int blk0, float invB) {
  __shared__ __align__(16) unsigned char sm_buf[2][32768];
  __shared__ __align__(16) float sm_u[128][4];
  __shared__ float sm_ts[9], sm_te[14], sm_tb[126];

  const int t = threadIdx.x;
  const int w = t >> 6, l = t & 63;
  const int hi = l >> 5, ln = l & 31;
  const int wm = w >> 3;
  const int wn = w & 7;
  const int rt = w & 3;
  const int jt = w >> 2;
  const int r0 = (blockIdx.x + blk0) * 128;

  float sv[2], cv[2], wv[2];
#pragma unroll
  for (int nf = 0; nf < 2; ++nf) {
    int col = wn * 64 + nf * 32 + ln;
    float mu = stat2[col] * invB;
    float ex2 = stat2[512 + col] * invB;
    float var = fmaxf(ex2 - mu * mu, 0.f);
    float s = g2[col] * rsqrtf(var + 1e-5f);
    sv[nf] = s * TANH_PRESCALE;
    cv[nf] = (be2[col] - mu * s) * TANH_PRESCALE;
    wv[nf] = w3g[col];
  }

  if (t < 9) sm_ts[t] = tsg[t];
  if (t < 14) sm_te[t] = teg[t];
  if (t < 126) sm_tb[t] = tbg[t];
  __syncthreads();

  if (t < 128) {
    const float* xr = x + (size_t)(r0 + t) * 15;
    float amb = xr[1], inc = xr[8];
    sm_u[t][0] = inter2d_d(sm_ts, sm_te, sm_tb, xr[2], amb) - inc;
    sm_u[t][1] = inter2d_d(sm_ts, sm_te, sm_tb, xr[3], amb) - inc;
    sm_u[t][2] = amb;
    sm_u[t][3] = xr[9] - xr[10];
  }
  __syncthreads();

  bf16x8 ufrag;
  {
    float4 uv = *(const float4*)&sm_u[rt * 32 + ln][0];
    u16 b0_ = f2bf(uv.x), b1_ = f2bf(uv.y), b2_ = f2bf(uv.z), b3_ = f2bf(uv.w);
    u32x4 uq;
    if (hi == 0) {
      uq[0] = (u32)b0_ | ((u32)b1_ << 16);
      uq[1] = (u32)b2_ | ((u32)b3_ << 16);
      uq[2] = 0x00003F80u | ((u32)b0_ << 16);
      uq[3] = (u32)b1_ | ((u32)b2_ << 16);
    } else {
      u16 d0 = f2bf(uv.x - bf2f(b0_)), d1 = f2bf(uv.y - bf2f(b1_));
      u16 d2 = f2bf(uv.z - bf2f(b2_)), d3 = f2bf(uv.w - bf2f(b3_));
      uq[0] = (u32)d0 | ((u32)d1 << 16);
      uq[1] = (u32)d2 | ((u32)d3 << 16);
      uq[2] = 0x00003F80u | ((u32)b3_ << 16);
      uq[3] = 0u;
    }
    ufrag = __builtin_bit_cast(bf16x8, uq);
  }

  u32 pq[8];
  auto produce_compute = [&](int sl) {
    bf16x8 af = *(const bf16x8*)(a1img +
        ((size_t)(sl * 128 + jt * 32 + ln) * 32 + hi * 16));
    f32x16 z = {};
    f32x16 d = __builtin_amdgcn_mfma_f32_32x32x16_bf16(af, ufrag, z, 0, 0, 0);
#pragma unroll
    for (int q = 0; q < 4; ++q) {
      pq[q * 2]     = cvtpk_bf16(tanh_pre(d[q * 4 + 0]), tanh_pre(d[q * 4 + 1]));
      pq[q * 2 + 1] = cvtpk_bf16(tanh_pre(d[q * 4 + 2]), tanh_pre(d[q * 4 + 3]));
    }
  };
  auto produce_write = [&](int sl) {
    unsigned char* dst = sm_buf[sl & 1];
#pragma unroll
    for (int q = 0; q < 4; ++q)
      *(uint2*)(dst + ((size_t)((jt * 4 + q) * 128 + rt * 32 + ln) * 16 + hi * 8)) =
          make_uint2(pq[q * 2], pq[q * 2 + 1]);
  };

  auto loadB = [&](uint4* dst, int ks) {
    const unsigned char* p = w2ts + ((size_t)(ks * 2 + hi) * 8192) +
                             (size_t)(wn * 64 + ln) * 16;
    dst[0] = *(const uint4*)(p);
    dst[1] = *(const uint4*)(p + 512);
  };

  f32x16 acc[4];
#pragma unroll
  for (int i = 0; i < 4; ++i)
#pragma unroll
    for (int k = 0; k < 16; ++k) acc[i][k] = 0.0f;

  uint4 bb[2][2];
  loadB(bb[0], 0);
  produce_compute(0);
  produce_write(0);
  __syncthreads();

#pragma unroll
  for (int sl = 0; sl < 4; ++sl) {
    const unsigned char* abuf = sm_buf[sl & 1];
#pragma unroll
    for (int s = 0; s < 8; ++s) {
      int ks = sl * 8 + s;
      if (ks < 31) loadB(bb[(ks + 1) & 1], ks + 1);
      const unsigned char* ab =
          abuf + ((size_t)(2 * s + hi) * 128 + wm * 64 + ln) * 16;
      bf16x8 a0 = *(const bf16x8*)(ab);
      bf16x8 a1 = *(const bf16x8*)(ab + 512);
#pragma unroll
      for (int nf = 0; nf < 2; ++nf) {
        bf16x8 bv = __builtin_bit_cast(bf16x8, bb[ks & 1][nf]);
        acc[0 + nf] = __builtin_amdgcn_mfma_f32_32x32x16_bf16(a0, bv, acc[0 + nf], 0, 0, 0);
        acc[2 + nf] = __builtin_amdgcn_mfma_f32_32x32x16_bf16(a1, bv, acc[2 + nf], 0, 0, 0);
      }
      if (sl < 3) {
        if (s == 0) produce_compute(sl + 1);
        if (s == 7) produce_write(sl + 1);
      }
    }
    __syncthreads();
  }

  float* pr = (float*)sm_buf[0];  // [128 rows][8 col-blocks]
#pragma unroll
  for (int mf = 0; mf < 2; ++mf)
#pragma unroll
    for (int k = 0; k < 16; ++k) {
      float v = tanh_pre(acc[mf * 2 + 0][k] * sv[0] + cv[0]) * wv[0] +
                tanh_pre(acc[mf * 2 + 1][k] * sv[1] + cv[1]) * wv[1];
      v += __shfl_xor(v, 1); v += __shfl_xor(v, 2); v += __shfl_xor(v, 4);
      v += __shfl_xor(v, 8); v += __shfl_xor(v, 16);
      if (ln == 0) {
        int row = wm * 64 + mf * 32 + (k & 3) + 8 * (k >> 2) + 4 * hi;
        pr[row * 8 + wn] = v;
      }
    }
  __syncthreads();
  if (t < 128) {
    float s = b3g[0];
#pragma unroll
    for (int i = 0; i < 8; ++i) s += pr[t * 8 + i];
    out[r0 + t] = s;
  }
}

// ---------- launcher ----------
extern "C" void kernel_launch(void* const* d_in, const int* in_sizes, int n_in,
                              void* d_out, int out_size, void* d_ws, size_t ws_size,
                              hipStream_t stream) {
  const float* x   = (const float*)d_in[0];
  const float* ts  = (const float*)d_in[1];
  const float* te  = (const float*)d_in[2];
  const float* tab = (const float*)d_in[3];
  const float* w1  = (const float*)d_in[4];
  const float* g1  = (const float*)d_in[6];
  const float* be1 = (const float*)d_in[7];
  const float* w2  = (const float*)d_in[8];
  const float* g2  = (const float*)d_in[10];
  const float* be2 = (const float*)d_in[11];
  const float* w3  = (const float*)d_in[12];
  const float* b3  = (const float*)d_in[13];
  float* out = (float*)d_out;
  char* ws = (char*)d_ws;

  if (ws_size < (size_t)(32768 + 524288)) return;

  int Bn = in_sizes[0] / 15;  // 262144
  float invB = 1.0f / (float)Bn;
  int ntiles = Bn / 128;      // 2048
  int nstat = Bn / 256;       // 1024

  float* mom   = (float*)(ws + 0);      // 14 f32 (zeroed)
  float* stat2 = (float*)(ws + 64);     // 1024 f32 (zeroed)
  unsigned char* a1img = (unsigned char*)(ws + 4160);  // 16 KB (512 j x 32B)
  unsigned char* w2ts = (unsigned char*)(ws + 32768);  // 512 KB bf16 image
  unsigned char* t2buf = (unsigned char*)(ws + (1 << 20));  // int8 t2 (adaptive)

  // adaptive: store as many int8 t2 tiles (66 KB each) as the workspace holds
  size_t avail = ws_size > (size_t)(1 << 20) ? ws_size - (size_t)(1 << 20) : 0;
  size_t cap = avail / (size_t)T2_TILE_BYTES;
  int nstore = cap >= (size_t)ntiles ? ntiles : (int)cap;

  (void)hipMemsetAsync(ws, 0, 4160, stream);
  pre_kernel<<<nstat + 128, 256, 0, stream>>>(x, ts, te, tab, mom, w2, w2ts, nstat);
  prep1_kernel<<<1, 512, 0, stream>>>(mom, w1, g1, be1, a1img, invB);
  gemm12_kernel<<<ntiles, 1024, 0, stream>>>(x, ts, te, tab, a1img, w2ts,
                                             stat2, t2buf, nstore);
  if (nstore > 0)
    finish_rb<<<nstore, 1024, 0, stream>>>(stat2, t2buf, g2, be2, w3, b3,
                                           out, invB);
  if (nstore < ntiles)
    finish_rc<<<ntiles - nstore, 1024, 0, stream>>>(
        x, ts, te, tab, a1img, w2ts, stat2, g2, be2, w3, b3, out,
        nstore, invB);
}

// Round 17
// 352.916 us; speedup vs baseline: 1.1867x; 1.0468x over previous
//
#include <hip/hip_runtime.h>

typedef unsigned int u32;
typedef unsigned short u16;
typedef __bf16 bf16x8 __attribute__((ext_vector_type(8)));
typedef float f32x16 __attribute__((ext_vector_type(16)));
typedef u32 u32x4 __attribute__((ext_vector_type(4)));
typedef _Float16 f16x2 __attribute__((ext_vector_type(2)));
typedef _Float16 f16x8 __attribute__((ext_vector_type(8)));

// K = 2*log2(e): folded into the layer-1 A-image and the BN2 scale/bias so
// tanh(x) = 1 - 2/(exp2(K*x)+1) needs zero multiplies at eval time.
#define TANH_PRESCALE 2.8853900817779268f
// per-tile t2 storage: 64 KB int8 fragments + 2 KB f16 per-thread scales
#define T2_TILE_BYTES 67584

// ---------- helpers ----------
__device__ __forceinline__ u16 f2bf(float f) {
  u32 u = __float_as_uint(f);
  u32 r = (u + 0x7FFFu + ((u >> 16) & 1u)) >> 16;
  return (u16)r;
}
__device__ __forceinline__ float bf2f(u16 h) {
  return __uint_as_float((u32)h << 16);
}
// single-instruction RNE bf16 pack (same rounding as f2bf)
__device__ __forceinline__ u32 cvtpk_bf16(float a, float b) {
  u32 r;
  asm("v_cvt_pk_bf16_f32 %0, %1, %2" : "=v"(r) : "v"(a), "v"(b));
  return r;
}
// tanh of x where v = TANH_PRESCALE * x has been pre-folded upstream
__device__ __forceinline__ float tanh_pre(float v) {
  float e = __builtin_exp2f(v);
  return 1.0f - 2.0f * __builtin_amdgcn_rcpf(e + 1.0f);
}

// bilinear interp matching jnp.searchsorted(side='right')-1 with clamping
__device__ __forceinline__ float inter2d_d(const float* xs, const float* ys,
                                           const float* tb, float xq, float yq) {
  xq = fminf(fmaxf(xq, xs[0]), xs[8]);
  yq = fminf(fmaxf(yq, ys[0]), ys[13]);
  int i = 0, j = 0;
#pragma unroll
  for (int k = 1; k <= 8; ++k) if (xq >= xs[k]) i = k;
#pragma unroll
  for (int k = 1; k <= 13; ++k) if (yq >= ys[k]) j = k;
  if (i > 7) i = 7;
  if (j > 12) j = 12;
  float x0 = xs[i], x1 = xs[i + 1], y0 = ys[j], y1 = ys[j + 1];
  float tx = (xq - x0) / (x1 - x0);
  float ty = (yq - y0) / (y1 - y0);
  float f00 = tb[i * 14 + j], f01 = tb[i * 14 + j + 1];
  float f10 = tb[(i + 1) * 14 + j], f11 = tb[(i + 1) * 14 + j + 1];
  return f00 * (1 - tx) * (1 - ty) + f10 * tx * (1 - ty) +
         f01 * (1 - tx) * ty + f11 * tx * ty;
}

// ---------- kernel 1: merged u-moments (blocks < nstat) + w2 transpose ----------
__global__ void pre_kernel(const float* __restrict__ x,
                           const float* __restrict__ tsg,
                           const float* __restrict__ teg,
                           const float* __restrict__ tbg,
                           float* __restrict__ mom,
                           const float* __restrict__ w2,
                           unsigned char* __restrict__ w2ts, int nstat) {
  __shared__ float ts[9], te[14], tb[126], bacc[14];
  int t = threadIdx.x;
  if ((int)blockIdx.x >= nstat) {
    int q = ((int)blockIdx.x - nstat) * 256 + t;  // 0..32767
    int n = q & 511;
    int kb = (q >> 9) * 8;
    u32 pk[4];
#pragma unroll
    for (int e = 0; e < 8; e += 2) {
      u16 a = f2bf(w2[(size_t)(kb + e) * 512 + n]);
      u16 b = f2bf(w2[(size_t)(kb + e + 1) * 512 + n]);
      pk[e >> 1] = (u32)a | ((u32)b << 16);
    }
    *(uint4*)(w2ts + (size_t)q * 16) = make_uint4(pk[0], pk[1], pk[2], pk[3]);
    return;
  }
  if (t < 9) ts[t] = tsg[t];
  if (t < 14) { te[t] = teg[t]; bacc[t] = 0.f; }
  if (t < 126) tb[t] = tbg[t];
  __syncthreads();
  const float* xr = x + (size_t)(blockIdx.x * 256 + t) * 15;
  float amb = xr[1], inc = xr[8];
  float u0 = inter2d_d(ts, te, tb, xr[2], amb) - inc;
  float u1 = inter2d_d(ts, te, tb, xr[3], amb) - inc;
  float u2 = amb, u3 = xr[9] - xr[10];
  float v[14] = {u0, u1, u2, u3,
                 u0 * u0, u0 * u1, u0 * u2, u0 * u3,
                 u1 * u1, u1 * u2, u1 * u3,
                 u2 * u2, u2 * u3, u3 * u3};
#pragma unroll
  for (int i = 0; i < 14; ++i) {
    float s = v[i];
    s += __shfl_xor(s, 32); s += __shfl_xor(s, 16); s += __shfl_xor(s, 8);
    s += __shfl_xor(s, 4);  s += __shfl_xor(s, 2);  s += __shfl_xor(s, 1);
    v[i] = s;
  }
  if ((t & 63) == 0)
    for (int i = 0; i < 14; ++i) atomicAdd(&bacc[i], v[i]);
  __syncthreads();
  if (t < 14) atomicAdd(&mom[t], bacc[t]);
}

// ---------- kernel 2: fold BN1 (and tanh prescale) into layer-1 A-image ----------
__global__ void prep1_kernel(const float* __restrict__ mom,
                             const float* __restrict__ w1,
                             const float* __restrict__ g1,
                             const float* __restrict__ be1,
                             unsigned char* __restrict__ a1img, float invB) {
  int j = threadIdx.x;  // 512
  float m0 = mom[0] * invB, m1 = mom[1] * invB, m2 = mom[2] * invB, m3 = mom[3] * invB;
  float C00 = mom[4]  * invB - m0 * m0, C01 = mom[5]  * invB - m0 * m1;
  float C02 = mom[6]  * invB - m0 * m2, C03 = mom[7]  * invB - m0 * m3;
  float C11 = mom[8]  * invB - m1 * m1, C12 = mom[9]  * invB - m1 * m2;
  float C13 = mom[10] * invB - m1 * m3, C22 = mom[11] * invB - m2 * m2;
  float C23 = mom[12] * invB - m2 * m3, C33 = mom[13] * invB - m3 * m3;
  float a = w1[j], b = w1[512 + j], c = w1[1024 + j], d = w1[1536 + j];
  float var = a * a * C00 + b * b * C11 + c * c * C22 + d * d * C33 +
              2.f * (a * b * C01 + a * c * C02 + a * d * C03 +
                     b * c * C12 + b * d * C13 + c * d * C23);
  float s1 = g1[j] * rsqrtf(fmaxf(var, 0.f) + 1e-5f) * TANH_PRESCALE;
  float a0 = a * s1, a1 = b * s1, a2 = c * s1, a3 = d * s1;
  float c1j = be1[j] * TANH_PRESCALE -
              (m0 * a + m1 * b + m2 * c + m3 * d) * s1;
  u16 ba0 = f2bf(a0), ba1 = f2bf(a1), ba2 = f2bf(a2), ba3 = f2bf(a3);
  u16 da0 = f2bf(a0 - bf2f(ba0)), da1 = f2bf(a1 - bf2f(ba1));
  u16 da2 = f2bf(a2 - bf2f(ba2)), da3 = f2bf(a3 - bf2f(ba3));
  u16 c1h = f2bf(c1j);
  u16 c1l = f2bf(c1j - bf2f(c1h));
  u32 p01 = (u32)ba0 | ((u32)ba1 << 16);
  u32 p23 = (u32)ba2 | ((u32)ba3 << 16);
  uint4* img = (uint4*)a1img;
  img[j * 2]     = make_uint4(p01, p23, (u32)c1h | ((u32)da0 << 16),
                              (u32)da1 | ((u32)da2 << 16));
  img[j * 2 + 1] = make_uint4(p01, p23, (u32)c1l | ((u32)da3 << 16), 0u);
}

// ---------- pass 1: fused t1 + GEMM(t1 @ w2), stats + int8 t2 dump ----------
// R8/R11/R15 geometry: 1024 threads = 16 waves = 2(M) x 8(N); wave tile
// 64x64 (2 mf x 2 nf, acc = 64 AGPR, ~4 waves/SIMD). Blocks < nstore store
// int8-quantized t2 fragments (one f16 scale per thread over its 64 values).
__global__ __launch_bounds__(1024) void gemm12_kernel(
    const float* __restrict__ x, const float* __restrict__ tsg,
    const float* __restrict__ teg, const float* __restrict__ tbg,
    const unsigned char* __restrict__ a1img,
    const unsigned char* __restrict__ w2ts, float* __restrict__ stat2,
    unsigned char* __restrict__ t2buf, int nstore) {
  __shared__ __align__(16) unsigned char sm_buf[2][32768];  // t1 slabs, chunk-major
  __shared__ __align__(16) float sm_u[128][4];
  __shared__ float sm_ts[9], sm_te[14], sm_tb[126];

  const int t = threadIdx.x;
  const int w = t >> 6, l = t & 63;
  const int hi = l >> 5, ln = l & 31;
  const int wm = w >> 3;         // consumer row-half (rows wm*64 .. +63)
  const int wn = w & 7;          // consumer col-block (cols wn*64 .. +63)
  const int rt = w & 3;          // production batch row-tile (rows rt*32..)
  const int jt = w >> 2;         // production j-tile (local 0..3)
  const int r0 = blockIdx.x * 128;

  if (t < 9) sm_ts[t] = tsg[t];
  if (t < 14) sm_te[t] = teg[t];
  if (t < 126) sm_tb[t] = tbg[t];
  __syncthreads();

  if (t < 128) {
    const float* xr = x + (size_t)(r0 + t) * 15;
    float amb = xr[1], inc = xr[8];
    sm_u[t][0] = inter2d_d(sm_ts, sm_te, sm_tb, xr[2], amb) - inc;
    sm_u[t][1] = inter2d_d(sm_ts, sm_te, sm_tb, xr[3], amb) - inc;
    sm_u[t][2] = amb;
    sm_u[t][3] = xr[9] - xr[10];
  }
  __syncthreads();

  // u B-frag for layer-1 MFMA: lane = batch row rt*32+ln.
  bf16x8 ufrag;
  {
    float4 uv = *(const float4*)&sm_u[rt * 32 + ln][0];
    u16 b0_ = f2bf(uv.x), b1_ = f2bf(uv.y), b2_ = f2bf(uv.z), b3_ = f2bf(uv.w);
    u32x4 uq;
    if (hi == 0) {
      uq[0] = (u32)b0_ | ((u32)b1_ << 16);
      uq[1] = (u32)b2_ | ((u32)b3_ << 16);
      uq[2] = 0x00003F80u | ((u32)b0_ << 16);
      uq[3] = (u32)b1_ | ((u32)b2_ << 16);
    } else {
      u16 d0 = f2bf(uv.x - bf2f(b0_)), d1 = f2bf(uv.y - bf2f(b1_));
      u16 d2 = f2bf(uv.z - bf2f(b2_)), d3 = f2bf(uv.w - bf2f(b3_));
      uq[0] = (u32)d0 | ((u32)d1 << 16);
      uq[1] = (u32)d2 | ((u32)d3 << 16);
      uq[2] = 0x00003F80u | ((u32)b3_ << 16);
      uq[3] = 0u;
    }
    ufrag = __builtin_bit_cast(bf16x8, uq);
  }

  // deferred-write production of the (rt, jt) 32x32 t1 tile of slab sl
  u32 pq[8];
  auto produce_compute = [&](int sl) {
    bf16x8 af = *(const bf16x8*)(a1img +
        ((size_t)(sl * 128 + jt * 32 + ln) * 32 + hi * 16));
    f32x16 z = {};
    f32x16 d = __builtin_amdgcn_mfma_f32_32x32x16_bf16(af, ufrag, z, 0, 0, 0);
#pragma unroll
    for (int q = 0; q < 4; ++q) {
      pq[q * 2]     = cvtpk_bf16(tanh_pre(d[q * 4 + 0]), tanh_pre(d[q * 4 + 1]));
      pq[q * 2 + 1] = cvtpk_bf16(tanh_pre(d[q * 4 + 2]), tanh_pre(d[q * 4 + 3]));
    }
  };
  auto produce_write = [&](int sl) {
    unsigned char* dst = sm_buf[sl & 1];
#pragma unroll
    for (int q = 0; q < 4; ++q)
      *(uint2*)(dst + ((size_t)((jt * 4 + q) * 128 + rt * 32 + ln) * 16 + hi * 8)) =
          make_uint2(pq[q * 2], pq[q * 2 + 1]);
  };

  // B frag loads: global K-octet G = ks*2 + hi; cols wn*64 + nf*32 + ln
  auto loadB = [&](uint4* dst, int ks) {
    const unsigned char* p = w2ts + ((size_t)(ks * 2 + hi) * 8192) +
                             (size_t)(wn * 64 + ln) * 16;
    dst[0] = *(const uint4*)(p);
    dst[1] = *(const uint4*)(p + 512);
  };

  f32x16 acc[4];  // [mf*2+nf]
#pragma unroll
  for (int i = 0; i < 4; ++i)
#pragma unroll
    for (int k = 0; k < 16; ++k) acc[i][k] = 0.0f;

  uint4 bb[2][2];
  loadB(bb[0], 0);
  produce_compute(0);
  produce_write(0);
  __syncthreads();

#pragma unroll
  for (int sl = 0; sl < 4; ++sl) {
    const unsigned char* abuf = sm_buf[sl & 1];
#pragma unroll
    for (int s = 0; s < 8; ++s) {
      int ks = sl * 8 + s;
      if (ks < 31) loadB(bb[(ks + 1) & 1], ks + 1);
      const unsigned char* ab =
          abuf + ((size_t)(2 * s + hi) * 128 + wm * 64 + ln) * 16;
      bf16x8 a0 = *(const bf16x8*)(ab);
      bf16x8 a1 = *(const bf16x8*)(ab + 512);
#pragma unroll
      for (int nf = 0; nf < 2; ++nf) {
        bf16x8 bv = __builtin_bit_cast(bf16x8, bb[ks & 1][nf]);
        acc[0 + nf] = __builtin_amdgcn_mfma_f32_32x32x16_bf16(a0, bv, acc[0 + nf], 0, 0, 0);
        acc[2 + nf] = __builtin_amdgcn_mfma_f32_32x32x16_bf16(a1, bv, acc[2 + nf], 0, 0, 0);
      }
      if (sl < 3) {
        if (s == 0) produce_compute(sl + 1);
        if (s == 7) produce_write(sl + 1);
      }
    }
    __syncthreads();
  }

  // C/D layout (32x32x16): col = lane&31, row_in_tile = (k&3) + 8*(k>>2) + 4*hi
  if (blockIdx.x < (u32)nstore) {
    // int8 t2 fragments: one scale per thread over its 64 acc values.
    float am = 0.f;
#pragma unroll
    for (int i = 0; i < 4; ++i)
#pragma unroll
      for (int k = 0; k < 16; ++k) am = fmaxf(am, fabsf(acc[i][k]));
    float inv = 127.0f / fmaxf(am, 1e-30f);
    unsigned char* tb8 = t2buf + (size_t)blockIdx.x * T2_TILE_BYTES;
    uint4* dst = (uint4*)tb8;
#pragma unroll
    for (int i = 0; i < 4; ++i) {
      u32 wd[4];
#pragma unroll
      for (int w4 = 0; w4 < 4; ++w4) {
        u32 b = 0;
#pragma unroll
        for (int j = 0; j < 4; ++j) {
          int q8 = (int)rintf(acc[i][w4 * 4 + j] * inv);
          b |= ((u32)(q8 & 0xFF)) << (8 * j);
        }
        wd[w4] = b;
      }
      dst[i * 1024 + t] = make_uint4(wd[0], wd[1], wd[2], wd[3]);
    }
    _Float16 sh = (_Float16)(am * (1.0f / 127.0f));
    *(u16*)(tb8 + 65536 + t * 2) = __builtin_bit_cast(u16, sh);
  }
  // column sums: wave covers rows wm*64..+63 for cols wn*64+nf*32+ln;
  // both wm halves atomically add (covers all 128 rows).
#pragma unroll
  for (int nf = 0; nf < 2; ++nf) {
    float s = 0.f, q = 0.f;
#pragma unroll
    for (int mf = 0; mf < 2; ++mf)
#pragma unroll
      for (int k = 0; k < 16; ++k) {
        float v = acc[mf * 2 + nf][k];
        s += v; q += v * v;
      }
    s += __shfl_xor(s, 32); q += __shfl_xor(q, 32);
    if (hi == 0) {
      int col = wn * 64 + nf * 32 + ln;
      atomicAdd(&stat2[col], s);
      atomicAdd(&stat2[512 + col], q);
    }
  }
}

// ---------- pass 2a: readback stored tiles (grid = nstore) ----------
// int8 dequant + tanh, then a TWO-PHASE float-LDS reduction (replaces the
// serial 5-shfl-per-k chains that were DS-latency-bound):
// Phase A: per thread, per k: nf-folded partial -> pp[lrow][wn*32+ln]
//          (stride 257 floats -> 2-way banks, free).
// Phase B: wave w sums 4 rows: 4 coalesced loads/lane + one 6-shfl reduce.
// All LDS accesses float-typed (R13 aliasing lesson).
__global__ __launch_bounds__(1024) void finish_rb(
    const float* __restrict__ stat2,
    const unsigned char* __restrict__ t2buf,
    const float* __restrict__ g2, const float* __restrict__ be2,
    const float* __restrict__ w3g, const float* __restrict__ b3g,
    float* __restrict__ out, float invB) {
  __shared__ float pp[64 * 257];  // 65.8 KB
  const int t = threadIdx.x;
  const int w = t >> 6, l = t & 63;
  const int hi = l >> 5, ln = l & 31;
  const int wm = w >> 3, wn = w & 7;
  const int r0 = blockIdx.x * 128;

  float sv[2], cv[2], wv[2];
#pragma unroll
  for (int nf = 0; nf < 2; ++nf) {
    int col = wn * 64 + nf * 32 + ln;
    float mu = stat2[col] * invB;
    float ex2 = stat2[512 + col] * invB;
    float var = fmaxf(ex2 - mu * mu, 0.f);
    float s = g2[col] * rsqrtf(var + 1e-5f);
    sv[nf] = s * TANH_PRESCALE;
    cv[nf] = (be2[col] - mu * s) * TANH_PRESCALE;
    wv[nf] = w3g[col];
  }
  const unsigned char* tb8 = t2buf + (size_t)blockIdx.x * T2_TILE_BYTES;
  const uint4* src = (const uint4*)tb8;
  uint4 ib[4];
#pragma unroll
  for (int p = 0; p < 4; ++p) ib[p] = src[p * 1024 + t];
  u16 sb = *(const u16*)(tb8 + 65536 + t * 2);
  float sc = (float)__builtin_bit_cast(_Float16, sb);
  float b3v = b3g[0];

#pragma unroll
  for (int mf = 0; mf < 2; ++mf) {
    if (mf) __syncthreads();  // protect pp reuse across halves
    // Phase A: nf-folded partial per k -> pp[lrow][wn*32+ln]
#pragma unroll
    for (int k = 0; k < 16; ++k) {
      float v = 0.f;
#pragma unroll
      for (int nf = 0; nf < 2; ++nf) {
        int p = mf * 2 + nf;
        u32 word = (&ib[p].x)[k >> 2];
        int q8 = (int)(char)((word >> (8 * (k & 3))) & 0xFFu);
        float a0 = (float)q8 * sc;
        v += tanh_pre(a0 * sv[nf] + cv[nf]) * wv[nf];
      }
      int lrow = wm * 32 + (k & 3) + 8 * (k >> 2) + 4 * hi;  // 0..63
      pp[lrow * 257 + wn * 32 + ln] = v;
    }
    __syncthreads();
    // Phase B: wave w owns rows w*4 .. w*4+3
#pragma unroll
    for (int rr = 0; rr < 4; ++rr) {
      int lrow = w * 4 + rr;
      const float* row = &pp[lrow * 257];
      float v = row[l] + row[l + 64] + row[l + 128] + row[l + 192];
      v += __shfl_xor(v, 1); v += __shfl_xor(v, 2); v += __shfl_xor(v, 4);
      v += __shfl_xor(v, 8); v += __shfl_xor(v, 16); v += __shfl_xor(v, 32);
      if (l == 0) {
        int grow = (lrow >> 5) * 64 + mf * 32 + (lrow & 31);
        out[r0 + grow] = b3v + v;
      }
    }
  }
}

// ---------- pass 2b: recompute tiles (grid = ntiles - nstore, offset blk0) ----------
__global__ __launch_bounds__(1024) void finish_rc(
    const float* __restrict__ x, const float* __restrict__ tsg,
    const float* __restrict__ teg, const float* __restrict__ tbg,
    const unsigned char* __restrict__ a1img,
    const unsigned char* __restrict__ w2ts,
    const float* __restrict__ stat2,
    const float* __restrict__ g2, const float* __restrict__ be2,
    const float* __restrict__ w3g, const float* __restrict__ b3g,
    float* __restrict__ out, int blk0, float invB) {
  __shared__ __align__(16) unsigned char sm_buf[2][32768];
  __shared__ __align__(16) float sm_u[128][4];
  __shared__ float sm_ts[9], sm_te[14], sm_tb[126];

  const int t = threadIdx.x;
  const int w = t >> 6, l = t & 63;
  const int hi = l >> 5, ln = l & 31;
  const int wm = w >> 3;
  const int wn = w & 7;
  const int rt = w & 3;
  const int jt = w >> 2;
  const int r0 = (blockIdx.x + blk0) * 128;

  float sv[2], cv[2], wv[2];
#pragma unroll
  for (int nf = 0; nf < 2; ++nf) {
    int col = wn * 64 + nf * 32 + ln;
    float mu = stat2[col] * invB;
    float ex2 = stat2[512 + col] * invB;
    float var = fmaxf(ex2 - mu * mu, 0.f);
    float s = g2[col] * rsqrtf(var + 1e-5f);
    sv[nf] = s * TANH_PRESCALE;
    cv[nf] = (be2[col] - mu * s) * TANH_PRESCALE;
    wv[nf] = w3g[col];
  }

  if (t < 9) sm_ts[t] = tsg[t];
  if (t < 14) sm_te[t] = teg[t];
  if (t < 126) sm_tb[t] = tbg[t];
  __syncthreads();

  if (t < 128) {
    const float* xr = x + (size_t)(r0 + t) * 15;
    float amb = xr[1], inc = xr[8];
    sm_u[t][0] = inter2d_d(sm_ts, sm_te, sm_tb, xr[2], amb) - inc;
    sm_u[t][1] = inter2d_d(sm_ts, sm_te, sm_tb, xr[3], amb) - inc;
    sm_u[t][2] = amb;
    sm_u[t][3] = xr[9] - xr[10];
  }
  __syncthreads();

  bf16x8 ufrag;
  {
    float4 uv = *(const float4*)&sm_u[rt * 32 + ln][0];
    u16 b0_ = f2bf(uv.x), b1_ = f2bf(uv.y), b2_ = f2bf(uv.z), b3_ = f2bf(uv.w);
    u32x4 uq;
    if (hi == 0) {
      uq[0] = (u32)b0_ | ((u32)b1_ << 16);
      uq[1] = (u32)b2_ | ((u32)b3_ << 16);
      uq[2] = 0x00003F80u | ((u32)b0_ << 16);
      uq[3] = (u32)b1_ | ((u32)b2_ << 16);
    } else {
      u16 d0 = f2bf(uv.x - bf2f(b0_)), d1 = f2bf(uv.y - bf2f(b1_));
      u16 d2 = f2bf(uv.z - bf2f(b2_)), d3 = f2bf(uv.w - bf2f(b3_));
      uq[0] = (u32)d0 | ((u32)d1 << 16);
      uq[1] = (u32)d2 | ((u32)d3 << 16);
      uq[2] = 0x00003F80u | ((u32)b3_ << 16);
      uq[3] = 0u;
    }
    ufrag = __builtin_bit_cast(bf16x8, uq);
  }

  u32 pq[8];
  auto produce_compute = [&](int sl) {
    bf16x8 af = *(const bf16x8*)(a1img +
        ((size_t)(sl * 128 + jt * 32 + ln) * 32 + hi * 16));
    f32x16 z = {};
    f32x16 d = __builtin_amdgcn_mfma_f32_32x32x16_bf16(af, ufrag, z, 0, 0, 0);
#pragma unroll
    for (int q = 0; q < 4; ++q) {
      pq[q * 2]     = cvtpk_bf16(tanh_pre(d[q * 4 + 0]), tanh_pre(d[q * 4 + 1]));
      pq[q * 2 + 1] = cvtpk_bf16(tanh_pre(d[q * 4 + 2]), tanh_pre(d[q * 4 + 3]));
    }
  };
  auto produce_write = [&](int sl) {
    unsigned char* dst = sm_buf[sl & 1];
#pragma unroll
    for (int q = 0; q < 4; ++q)
      *(uint2*)(dst + ((size_t)((jt * 4 + q) * 128 + rt * 32 + ln) * 16 + hi * 8)) =
          make_uint2(pq[q * 2], pq[q * 2 + 1]);
  };

  auto loadB = [&](uint4* dst, int ks) {
    const unsigned char* p = w2ts + ((size_t)(ks * 2 + hi) * 8192) +
                             (size_t)(wn * 64 + ln) * 16;
    dst[0] = *(const uint4*)(p);
    dst[1] = *(const uint4*)(p + 512);
  };

  f32x16 acc[4];
#pragma unroll
  for (int i = 0; i < 4; ++i)
#pragma unroll
    for (int k = 0; k < 16; ++k) acc[i][k] = 0.0f;

  uint4 bb[2][2];
  loadB(bb[0], 0);
  produce_compute(0);
  produce_write(0);
  __syncthreads();

#pragma unroll
  for (int sl = 0; sl < 4; ++sl) {
    const unsigned char* abuf = sm_buf[sl & 1];
#pragma unroll
    for (int s = 0; s < 8; ++s) {
      int ks = sl * 8 + s;
      if (ks < 31) loadB(bb[(ks + 1) & 1], ks + 1);
      const unsigned char* ab =
          abuf + ((size_t)(2 * s + hi) * 128 + wm * 64 + ln) * 16;
      bf16x8 a0 = *(const bf16x8*)(ab);
      bf16x8 a1 = *(const bf16x8*)(ab + 512);
#pragma unroll
      for (int nf = 0; nf < 2; ++nf) {
        bf16x8 bv = __builtin_bit_cast(bf16x8, bb[ks & 1][nf]);
        acc[0 + nf] = __builtin_amdgcn_mfma_f32_32x32x16_bf16(a0, bv, acc[0 + nf], 0, 0, 0);
        acc[2 + nf] = __builtin_amdgcn_mfma_f32_32x32x16_bf16(a1, bv, acc[2 + nf], 0, 0, 0);
      }
      if (sl < 3) {
        if (s == 0) produce_compute(sl + 1);
        if (s == 7) produce_write(sl + 1);
      }
    }
    __syncthreads();
  }

  float* pr = (float*)sm_buf[0];  // [128 rows][8 col-blocks]
#pragma unroll
  for (int mf = 0; mf < 2; ++mf)
#pragma unroll
    for (int k = 0; k < 16; ++k) {
      float v = tanh_pre(acc[mf * 2 + 0][k] * sv[0] + cv[0]) * wv[0] +
                tanh_pre(acc[mf * 2 + 1][k] * sv[1] + cv[1]) * wv[1];
      v += __shfl_xor(v, 1); v += __shfl_xor(v, 2); v += __shfl_xor(v, 4);
      v += __shfl_xor(v, 8); v += __shfl_xor(v, 16);
      if (ln == 0) {
        int row = wm * 64 + mf * 32 + (k & 3) + 8 * (k >> 2) + 4 * hi;
        pr[row * 8 + wn] = v;
      }
    }
  __syncthreads();
  if (t < 128) {
    float s = b3g[0];
#pragma unroll
    for (int i = 0; i < 8; ++i) s += pr[t * 8 + i];
    out[r0 + t] = s;
  }
}

// ---------- launcher ----------
extern "C" void kernel_launch(void* const* d_in, const int* in_sizes, int n_in,
                              void* d_out, int out_size, void* d_ws, size_t ws_size,
                              hipStream_t stream) {
  const float* x   = (const float*)d_in[0];
  const float* ts  = (const float*)d_in[1];
  const float* te  = (const float*)d_in[2];
  const float* tab = (const float*)d_in[3];
  const float* w1  = (const float*)d_in[4];
  const float* g1  = (const float*)d_in[6];
  const float* be1 = (const float*)d_in[7];
  const float* w2  = (const float*)d_in[8];
  const float* g2  = (const float*)d_in[10];
  const float* be2 = (const float*)d_in[11];
  const float* w3  = (const float*)d_in[12];
  const float* b3  = (const float*)d_in[13];
  float* out = (float*)d_out;
  char* ws = (char*)d_ws;

  if (ws_size < (size_t)(32768 + 524288)) return;

  int Bn = in_sizes[0] / 15;  // 262144
  float invB = 1.0f / (float)Bn;
  int ntiles = Bn / 128;      // 2048
  int nstat = Bn / 256;       // 1024

  float* mom   = (float*)(ws + 0);      // 14 f32 (zeroed)
  float* stat2 = (float*)(ws + 64);     // 1024 f32 (zeroed)
  unsigned char* a1img = (unsigned char*)(ws + 4160);  // 16 KB (512 j x 32B)
  unsigned char* w2ts = (unsigned char*)(ws + 32768);  // 512 KB bf16 image
  unsigned char* t2buf = (unsigned char*)(ws + (1 << 20));  // int8 t2 (adaptive)

  // adaptive: store as many int8 t2 tiles (66 KB each) as the workspace holds
  size_t avail = ws_size > (size_t)(1 << 20) ? ws_size - (size_t)(1 << 20) : 0;
  size_t cap = avail / (size_t)T2_TILE_BYTES;
  int nstore = cap >= (size_t)ntiles ? ntiles : (int)cap;

  (void)hipMemsetAsync(ws, 0, 4160, stream);
  pre_kernel<<<nstat + 128, 256, 0, stream>>>(x, ts, te, tab, mom, w2, w2ts, nstat);
  prep1_kernel<<<1, 512, 0, stream>>>(mom, w1, g1, be1, a1img, invB);
  gemm12_kernel<<<ntiles, 1024, 0, stream>>>(x, ts, te, tab, a1img, w2ts,
                                             stat2, t2buf, nstore);
  if (nstore > 0)
    finish_rb<<<nstore, 1024, 0, stream>>>(stat2, t2buf, g2, be2, w3, b3,
                                           out, invB);
  if (nstore < ntiles)
    finish_rc<<<ntiles - nstore, 1024, 0, stream>>>(
        x, ts, te, tab, a1img, w2ts, stat2, g2, be2, w3, b3, out,
        nstore, invB);
}